// Round 8
// baseline (279.992 us; speedup 1.0000x reference)
//
#include <hip/hip_runtime.h>
#include <math.h>

#define B_ 4
#define S_ 2048
#define E_ 512
#define H_ 8
#define Dh_ 64
#define BS_ (B_*S_)
#define MAXN 0.996f   // (1 - 4e-3)/sqrt(c), c=1

typedef __attribute__((ext_vector_type(8))) short short8;
typedef __attribute__((ext_vector_type(4))) float f32x4;

__device__ __forceinline__ float wave_reduce_sum(float v) {
  #pragma unroll
  for (int off = 32; off > 0; off >>= 1) v += __shfl_xor(v, off, 64);
  return v;
}

__device__ __forceinline__ unsigned f2bf(float x) {            // RNE f32->bf16 bits
  unsigned u = __float_as_uint(x);
  return (u + 0x7fffu + ((u >> 16) & 1u)) >> 16;
}
__device__ __forceinline__ float bf2f(unsigned b) {
  return __uint_as_float(b << 16);
}

__device__ __forceinline__ void gload_lds16(const void* g, void* lds) {
  __builtin_amdgcn_global_load_lds(
      (const __attribute__((address_space(1))) unsigned int*)g,
      (__attribute__((address_space(3))) unsigned int*)lds, 16, 0, 0);
}

// ---- per-row stats: xn = max(||row||,1e-15), art = artanh(clip(xn))
__global__ __launch_bounds__(256) void row_stats_kernel(const float* __restrict__ X,
                                                        float* __restrict__ xn_out,
                                                        float* __restrict__ art_out) {
  int row = blockIdx.x * 4 + (threadIdx.x >> 6);
  int lane = threadIdx.x & 63;
  const float4* xr = (const float4*)(X + (size_t)row * E_) + lane * 2;
  float4 a = xr[0], b = xr[1];
  float s = a.x*a.x + a.y*a.y + a.z*a.z + a.w*a.w
          + b.x*b.x + b.y*b.y + b.z*b.z + b.w*b.w;
  s = wave_reduce_sum(s);
  if (lane == 0) {
    float xn = fmaxf(sqrtf(s), 1e-15f);
    float aa = fminf(xn, 1.f - 1e-7f);
    xn_out[row] = xn;
    art_out[row] = 0.5f * (log1pf(aa) - log1pf(-aa));
  }
}

// ---- pack W matrices: t-major B-frag order (contiguous 64KB per K-step)
// Wp[mat][ ((t*32 + n)*2 + hl)*512 + l*8 + j ]
// element: W[16n + (l&15)][32t + 8*(l>>4) + j]
__global__ __launch_bounds__(64) void pack_w_kernel(const float* __restrict__ W0,
    const float* __restrict__ W1, const float* __restrict__ W2,
    const float* __restrict__ W3, unsigned short* __restrict__ Wp) {
  const float* W = (blockIdx.y == 0) ? W0 : (blockIdx.y == 1) ? W1
                 : (blockIdx.y == 2) ? W2 : W3;
  unsigned short* dst = Wp + (size_t)blockIdx.y * 524288;
  int l = threadIdx.x;
  int n = blockIdx.x;
  int col = 16*n + (l & 15);
  int k0 = 8 * (l >> 4);
  #pragma unroll 1
  for (int t = 0; t < 16; ++t) {
    const float* wp_ = W + (size_t)col * E_ + 32*t + k0;
    float4 a0 = *(const float4*)wp_, a1 = *(const float4*)(wp_ + 4);
    float av[8] = {a0.x,a0.y,a0.z,a0.w,a1.x,a1.y,a1.z,a1.w};
    short8 hi, lo;
    #pragma unroll
    for (int j = 0; j < 8; ++j) {
      unsigned hb = f2bf(av[j]);
      hi[j] = (short)hb;
      lo[j] = (short)f2bf(av[j] - bf2f(hb));
    }
    unsigned short* o = dst + ((size_t)(t*32 + n)*2)*512 + l*8;
    *(short8*)o = hi;
    *(short8*)(o + 512) = lo;
  }
}

// ---- hyp_linear v5 (unchanged from round 7): 16-wave M=32, single-buffer W
// via global_load_lds, X depth-2 register prefetch.
template<int MODE>
__global__ __launch_bounds__(1024, 4) void hyp_linear_pack(const float* __restrict__ X,
    const unsigned short* __restrict__ Wp, const float* __restrict__ bvec,
    const float* __restrict__ xn_arr, const float* __restrict__ art_arr,
    float* __restrict__ outF, unsigned short* __restrict__ outHi,
    float* __restrict__ normOut) {
  __shared__ __align__(16) unsigned short Wt[32768];   // 64KB, single buffer
  __shared__ float smM[8][2][4][4], smB[8][2][4][4], smb2[16];
  int tid = threadIdx.x;
  int w = tid >> 6, l = tid & 63;
  int l15 = l & 15, g = l >> 4;
  int rh = w & 1, ng = w >> 1;
  int R = blockIdx.x;                       // rows 32R .. 32R+31

  f32x4 acc[4];
  #pragma unroll
  for (int s = 0; s < 4; ++s) acc[s] = (f32x4){0.f,0.f,0.f,0.f};
  const float* xrow = X + (size_t)(R*32 + rh*16 + l15)*E_ + 8*g;

  float4 xa0 = *(const float4*)(xrow);          // t=0
  float4 xa1 = *(const float4*)(xrow + 4);
  float4 xb0 = *(const float4*)(xrow + 32);     // t=1
  float4 xb1 = *(const float4*)(xrow + 36);

  auto step = [&](int t, float4& c0, float4& c1) {
    __syncthreads();                            // all reads of Wt done
    const unsigned short* src = Wp + (size_t)t*32768 + w*512 + l*8;
    #pragma unroll
    for (int r = 0; r < 4; ++r)
      gload_lds16(src + r*8192, &Wt[r*8192 + w*512]);
    float av[8] = {c0.x,c0.y,c0.z,c0.w,c1.x,c1.y,c1.z,c1.w};
    short8 ahi, alo;
    #pragma unroll
    for (int j = 0; j < 8; ++j) {
      unsigned hb = f2bf(av[j]);
      ahi[j] = (short)hb;
      alo[j] = (short)f2bf(av[j] - bf2f(hb));
    }
    asm volatile("s_waitcnt vmcnt(0)" ::: "memory");
    __syncthreads();
    // prefetch X(t+2) into the regs just consumed; hidden under compute
    if (t < 14) {
      c0 = *(const float4*)(xrow + 32*(t+2));
      c1 = *(const float4*)(xrow + 32*(t+2) + 4);
    }
    const unsigned short* wb = &Wt[(8*ng)*512] + l*8;
    #pragma unroll
    for (int s = 0; s < 4; ++s) {
      short8 bhi = *(const short8*)(wb + (2*s)*512);
      short8 blo = *(const short8*)(wb + (2*s+1)*512);
      acc[s] = __builtin_amdgcn_mfma_f32_16x16x32_bf16(ahi, bhi, acc[s], 0, 0, 0);
      acc[s] = __builtin_amdgcn_mfma_f32_16x16x32_bf16(ahi, blo, acc[s], 0, 0, 0);
      acc[s] = __builtin_amdgcn_mfma_f32_16x16x32_bf16(alo, bhi, acc[s], 0, 0, 0);
    }
  };
  #pragma unroll 1
  for (int tt = 0; tt < 16; tt += 2) {
    step(tt,   xa0, xa1);
    step(tt+1, xb0, xb1);
  }

  // ---- epilogue scalars (rows rh*16 + 4g+i; cols 16*(4ng+s)+l15)
  float bl[4];
  #pragma unroll
  for (int s = 0; s < 4; ++s) bl[s] = bvec[16*(4*ng+s) + l15];
  float m2p[4] = {0.f,0.f,0.f,0.f}, mbp[4] = {0.f,0.f,0.f,0.f}, b2p = 0.f;
  #pragma unroll
  for (int s = 0; s < 4; ++s) {
    b2p += bl[s]*bl[s];
    #pragma unroll
    for (int i = 0; i < 4; ++i) {
      m2p[i] = fmaf(acc[s][i], acc[s][i], m2p[i]);
      mbp[i] = fmaf(acc[s][i], bl[s], mbp[i]);
    }
  }
  #pragma unroll
  for (int off = 1; off <= 8; off <<= 1) {
    b2p += __shfl_xor(b2p, off, 64);
    #pragma unroll
    for (int i = 0; i < 4; ++i) {
      m2p[i] += __shfl_xor(m2p[i], off, 64);
      mbp[i] += __shfl_xor(mbp[i], off, 64);
    }
  }
  if (l == 0) smb2[w] = b2p;
  if (l15 == 0) {
    #pragma unroll
    for (int i = 0; i < 4; ++i) { smM[ng][rh][g][i] = m2p[i]; smB[ng][rh][g][i] = mbp[i]; }
  }
  __syncthreads();
  float b2 = 0.f;
  #pragma unroll
  for (int n2i = 0; n2i < 8; ++n2i) b2 += smb2[2*n2i];   // rh=0 copies
  float G[4], Hc[4];
  #pragma unroll
  for (int i = 0; i < 4; ++i) {
    float m2 = 0.f, mb = 0.f;
    #pragma unroll
    for (int n2i = 0; n2i < 8; ++n2i) { m2 += smM[n2i][rh][g][i]; mb += smB[n2i][rh][g][i]; }
    int row = R*32 + rh*16 + 4*g + i;
    float xn = xn_arr[row], art = art_arr[row];
    float mn = fmaxf(sqrtf(m2), 1e-15f);
    float t = tanhf(mn / xn * art);
    float alpha, rn;
    if (m2 > 0.f) { alpha = t / mn; rn = t; } else { alpha = 0.f; rn = 0.f; }
    if (rn > MAXN) { alpha *= MAXN / rn; rn = MAXN; }          // project(res)
    float x2r = rn * rn;
    float xy = alpha * mb;
    float A  = 1.f + 2.f*xy + b2;
    float Bc = 1.f - x2r;
    float den = fmaxf(1.f + 2.f*xy + x2r*b2, 1e-15f);
    float n2v = (A*A*x2r + 2.f*A*Bc*xy + Bc*Bc*b2) / (den*den);
    float nn = fmaxf(sqrtf(n2v), 1e-15f);
    float sc = (nn > MAXN) ? (MAXN / nn) : 1.f;                // project(add)
    G[i]  = sc * A * alpha / den;
    Hc[i] = sc * Bc / den;
  }

  // ---- outputs (head h == ng for MODE 1/2)
  #pragma unroll
  for (int i = 0; i < 4; ++i) {
    int grow = R*32 + rh*16 + 4*g + i;
    if (MODE == 3) {
      #pragma unroll
      for (int s = 0; s < 4; ++s)
        outF[(size_t)grow*E_ + 16*(4*ng+s) + l15] = G[i]*acc[s][i] + Hc[i]*bl[s];
    } else {
      int bb = grow >> 11, seq = grow & 2047;
      int tile = seq >> 6;
      float hn = 0.f;
      #pragma unroll
      for (int s = 0; s < 4; ++s) {
        int col = 16*(4*ng+s) + l15;
        float v = G[i]*acc[s][i] + Hc[i]*bl[s];
        int h = col >> 6, c = col & 63;
        size_t base;
        if (MODE == 2) {   // V layout
          int kt = (seq >> 5) & 1, gp = (seq >> 3) & 3, jv = seq & 7;
          int dn = c >> 4, lt = (c & 15) | (gp << 4);
          base = ((size_t)((bb*8 + h)*32 + tile))*4096 + (size_t)((kt*4+dn)*64 + lt)*8 + jv;
        } else {           // Q/K layout
          int nf = (seq >> 4) & 3, lt15 = seq & 15;
          int dt = c >> 5, m = (c >> 3) & 3, j = c & 7;
          base = ((size_t)((bb*8 + h)*32 + tile))*4096 + (size_t)((dt*4+nf)*64 + (lt15|(m<<4)))*8 + j;
        }
        outHi[base] = (unsigned short)f2bf(v);
        if (MODE == 1) hn += v*v;
      }
      if (MODE == 1) {
        hn += __shfl_xor(hn,1,64); hn += __shfl_xor(hn,2,64);
        hn += __shfl_xor(hn,4,64); hn += __shfl_xor(hn,8,64);
        if (l15 == 0)
          normOut[((size_t)(bb*8 + ng))*S_ + seq] = fminf(hn, 1.f - 1e-5f);
      }
    }
  }
}

// ---- Attention v7: r6-proven P path (manual RNE f2bf, l from rounded p),
// gload_lds staging with kn issued FIRST (staging stays in flight past kn wait),
// explicit vmcnt(0) fence before the tile barrier. 40KB LDS -> 4 blocks/CU.
__global__ __launch_bounds__(256, 4) void attn_kernel(
    const unsigned short* __restrict__ Qhi, const unsigned short* __restrict__ Khi,
    const unsigned short* __restrict__ Vhi,
    const float* __restrict__ qn_arr, const float* __restrict__ kn_arr,
    float* __restrict__ Out) {
  __shared__ __align__(16) unsigned short Kf[2][4096], Vf[2][4096];
  __shared__ __align__(16) unsigned short Pf[4][1024];

  int tid = threadIdx.x;
  int w = tid >> 6, l = tid & 63;
  int l15 = l & 15, g = l >> 4;

  int bid = blockIdx.x;                 // XCD swizzle: xcd owns bh 4*xcd..4*xcd+3
  int xcd = bid & 7, idx = bid >> 3;
  int bh = xcd * 4 + (idx >> 5);
  int qblk = idx & 31;
  int b = bh >> 3, h = bh & 7;
  int qb = qblk * 64;

  const unsigned short* qbase = Qhi + ((size_t)(bh*32 + qblk))*4096;
  short8 qhi[2];
  #pragma unroll
  for (int dt = 0; dt < 2; ++dt)
    qhi[dt] = *(const short8*)(qbase + (size_t)((dt*4 + w)*64 + l)*8);
  float qnv[4], qd[4];
  #pragma unroll
  for (int i = 0; i < 4; ++i) {
    qnv[i] = qn_arr[(size_t)bh*S_ + qb + 16*w + 4*g + i];
    qd[i] = 1.f - qnv[i];
  }

  f32x4 Oacc[4];
  #pragma unroll
  for (int dn = 0; dn < 4; ++dn) Oacc[dn] = (f32x4){0.f,0.f,0.f,0.f};
  float lp[4] = {0.f,0.f,0.f,0.f};

  const unsigned short* Kbh = Khi + ((size_t)bh*32)*4096;
  const unsigned short* Vbh = Vhi + ((size_t)bh*32)*4096;
  const float* knp = kn_arr + (size_t)bh*S_;

  // prologue: stage tile 0 via global_load_lds (verbatim linear copy)
  #pragma unroll
  for (int r = 0; r < 2; ++r) {
    gload_lds16(Kbh + r*2048 + w*512 + l*8, &Kf[0][r*2048 + w*512]);
    gload_lds16(Vbh + r*2048 + w*512 + l*8, &Vf[0][r*2048 + w*512]);
  }
  asm volatile("s_waitcnt vmcnt(0)" ::: "memory");
  __syncthreads();

  #pragma unroll 1
  for (int tile = 0; tile < 32; ++tile) {
    int cur = tile & 1;
    int kb = tile * 64;
    float knc[4];
    #pragma unroll
    for (int n = 0; n < 4; ++n) knc[n] = knp[kb + 16*n + l15];  // issue BEFORE staging
    if (tile < 31) {                    // issue stage of tile+1 into buf^1
      const unsigned short* kp = Kbh + ((size_t)(tile+1))*4096;
      const unsigned short* vp = Vbh + ((size_t)(tile+1))*4096;
      #pragma unroll
      for (int r = 0; r < 2; ++r) {
        gload_lds16(kp + r*2048 + w*512 + l*8, &Kf[cur^1][r*2048 + w*512]);
        gload_lds16(vp + r*2048 + w*512 + l*8, &Vf[cur^1][r*2048 + w*512]);
      }
    }
    // ---- QK^T + softmax + P store
    #pragma unroll
    for (int n = 0; n < 4; ++n) {
      f32x4 Cn = (f32x4){0.f,0.f,0.f,0.f};
      #pragma unroll
      for (int dt = 0; dt < 2; ++dt) {
        short8 kfr = *(const short8*)&Kf[cur][((dt*4 + n)*64 + l)*8];
        Cn = __builtin_amdgcn_mfma_f32_16x16x32_bf16(qhi[dt], kfr, Cn, 0, 0, 0);
      }
      float kd = 1.f - knc[n];
      int cbase = (n >> 1)*64 + 16*((2*n + (l15 >> 3)) & 3) + 4*g;
      int csb = cbase ^ ((cbase >> 3) & 7);      // cs_i = csb ^ i
      int j7 = l15 & 7;
      #pragma unroll
      for (int i = 0; i < 4; ++i) {
        float den = fmaf(qd[i], kd, 1e-5f);
        float r = __builtin_amdgcn_rcpf(den);
        float num = fmaf(-qnv[i], knc[n], Cn[i]);
        float delta = fmaxf(2.f*num*r, 1e-5f);
        float sq = delta * __builtin_amdgcn_rsqf(delta);       // sqrt(delta)
        float p = __builtin_amdgcn_exp2f(-0.18033688f * sq);   // exp(-sqrt/8)
        unsigned hb = f2bf(p);
        lp[i] += bf2f(hb);                                     // consistent num/den
        Pf[w][((csb ^ i) << 3) + j7] = (unsigned short)hb;
      }
    }
    // ---- PV
    short8 pa0, pa1;
    { int c = l;       int cs = c ^ ((c >> 3) & 7); pa0 = *(const short8*)&Pf[w][cs*8]; }
    { int c = 64 + l;  int cs = c ^ ((c >> 3) & 7); pa1 = *(const short8*)&Pf[w][cs*8]; }
    #pragma unroll
    for (int dn = 0; dn < 4; ++dn) {
      short8 v0 = *(const short8*)&Vf[cur][((0*4 + dn)*64 + l)*8];
      short8 v1 = *(const short8*)&Vf[cur][((1*4 + dn)*64 + l)*8];
      f32x4 o = Oacc[dn];
      o = __builtin_amdgcn_mfma_f32_16x16x32_bf16(pa0, v0, o, 0, 0, 0);
      o = __builtin_amdgcn_mfma_f32_16x16x32_bf16(pa1, v1, o, 0, 0, 0);
      Oacc[dn] = o;
    }
    asm volatile("s_waitcnt vmcnt(0)" ::: "memory");   // explicit staging fence
    __syncthreads();
  }

  #pragma unroll
  for (int i = 0; i < 4; ++i) {
    lp[i] += __shfl_xor(lp[i], 1, 64);
    lp[i] += __shfl_xor(lp[i], 2, 64);
    lp[i] += __shfl_xor(lp[i], 4, 64);
    lp[i] += __shfl_xor(lp[i], 8, 64);
    lp[i] = 1.f / lp[i];
  }
  #pragma unroll
  for (int i = 0; i < 4; ++i) {
    size_t orow = (size_t)(b*S_ + qb + 16*w + 4*g + i)*E_ + h*Dh_;
    #pragma unroll
    for (int dn = 0; dn < 4; ++dn)
      Out[orow + 16*dn + l15] = Oacc[dn][i] * lp[i];
  }
}

extern "C" void kernel_launch(void* const* d_in, const int* in_sizes, int n_in,
                              void* d_out, int out_size, void* d_ws, size_t ws_size,
                              hipStream_t stream) {
  const float* x  = (const float*)d_in[0];
  const float* Wq = (const float*)d_in[1];
  const float* bq = (const float*)d_in[2];
  const float* Wk = (const float*)d_in[3];
  const float* bk = (const float*)d_in[4];
  const float* Wv = (const float*)d_in[5];
  const float* bv = (const float*)d_in[6];
  const float* Wo = (const float*)d_in[7];
  const float* bo = (const float*)d_in[8];
  float* out = (float*)d_out;

  char* p = (char*)d_ws;
  unsigned short* Wp  = (unsigned short*)p; p += (size_t)4  << 20;  // 4 MB
  unsigned short* Qhi = (unsigned short*)p; p += (size_t)8  << 20;
  unsigned short* Khi = (unsigned short*)p; p += (size_t)8  << 20;
  unsigned short* Vhi = (unsigned short*)p; p += (size_t)8  << 20;
  float* ao   = (float*)p; p += (size_t)16 << 20;                   // attn out fp32
  float* xn   = (float*)p; p += BS_ * 4;
  float* art  = (float*)p; p += BS_ * 4;
  float* xn2  = (float*)p; p += BS_ * 4;
  float* art2 = (float*)p; p += BS_ * 4;
  float* qn   = (float*)p; p += (size_t)B_*H_*S_ * 4;
  float* kn   = (float*)p; p += (size_t)B_*H_*S_ * 4;
  // total ~= 44.6 MB

  pack_w_kernel<<<dim3(32, 4), dim3(64), 0, stream>>>(Wq, Wk, Wv, Wo, Wp);
  row_stats_kernel<<<dim3(BS_/4), dim3(256), 0, stream>>>(x, xn, art);
  hyp_linear_pack<1><<<dim3(BS_/32), dim3(1024), 0, stream>>>(x, Wp,            bq, xn, art, nullptr, Qhi, qn);
  hyp_linear_pack<1><<<dim3(BS_/32), dim3(1024), 0, stream>>>(x, Wp + 524288,   bk, xn, art, nullptr, Khi, kn);
  hyp_linear_pack<2><<<dim3(BS_/32), dim3(1024), 0, stream>>>(x, Wp + 2*524288, bv, xn, art, nullptr, Vhi, nullptr);
  attn_kernel<<<dim3(1024), dim3(256), 0, stream>>>(Qhi, Khi, Vhi, qn, kn, ao);
  row_stats_kernel<<<dim3(BS_/4), dim3(256), 0, stream>>>(ao, xn2, art2);
  hyp_linear_pack<3><<<dim3(BS_/32), dim3(1024), 0, stream>>>(ao, Wp + 3*524288, bo, xn2, art2, out, nullptr, nullptr);
}

// Round 9
// 259.485 us; speedup vs baseline: 1.0790x; 1.0790x over previous
//
#include <hip/hip_runtime.h>
#include <math.h>

#define B_ 4
#define S_ 2048
#define E_ 512
#define H_ 8
#define Dh_ 64
#define BS_ (B_*S_)
#define MAXN 0.996f   // (1 - 4e-3)/sqrt(c), c=1

typedef __attribute__((ext_vector_type(8))) short short8;
typedef __attribute__((ext_vector_type(4))) float f32x4;

__device__ __forceinline__ float wave_reduce_sum(float v) {
  #pragma unroll
  for (int off = 32; off > 0; off >>= 1) v += __shfl_xor(v, off, 64);
  return v;
}

__device__ __forceinline__ unsigned f2bf(float x) {            // RNE f32->bf16 bits
  unsigned u = __float_as_uint(x);
  return (u + 0x7fffu + ((u >> 16) & 1u)) >> 16;
}
__device__ __forceinline__ float bf2f(unsigned b) {
  return __uint_as_float(b << 16);
}

__device__ __forceinline__ void gload_lds16(const void* g, void* lds) {
  __builtin_amdgcn_global_load_lds(
      (const __attribute__((address_space(1))) unsigned int*)g,
      (__attribute__((address_space(3))) unsigned int*)lds, 16, 0, 0);
}

// ---- per-row stats: xn = max(||row||,1e-15), art = artanh(clip(xn))
__global__ __launch_bounds__(256) void row_stats_kernel(const float* __restrict__ X,
                                                        float* __restrict__ xn_out,
                                                        float* __restrict__ art_out) {
  int row = blockIdx.x * 4 + (threadIdx.x >> 6);
  int lane = threadIdx.x & 63;
  const float4* xr = (const float4*)(X + (size_t)row * E_) + lane * 2;
  float4 a = xr[0], b = xr[1];
  float s = a.x*a.x + a.y*a.y + a.z*a.z + a.w*a.w
          + b.x*b.x + b.y*b.y + b.z*b.z + b.w*b.w;
  s = wave_reduce_sum(s);
  if (lane == 0) {
    float xn = fmaxf(sqrtf(s), 1e-15f);
    float aa = fminf(xn, 1.f - 1e-7f);
    xn_out[row] = xn;
    art_out[row] = 0.5f * (log1pf(aa) - log1pf(-aa));
  }
}

// ---- pack W matrices: t-major B-frag order (contiguous 64KB per K-step)
// Wp[mat][ ((t*32 + n)*2 + hl)*512 + l*8 + j ]
// element: W[16n + (l&15)][32t + 8*(l>>4) + j]
__global__ __launch_bounds__(64) void pack_w_kernel(const float* __restrict__ W0,
    const float* __restrict__ W1, const float* __restrict__ W2,
    const float* __restrict__ W3, unsigned short* __restrict__ Wp) {
  const float* W = (blockIdx.y == 0) ? W0 : (blockIdx.y == 1) ? W1
                 : (blockIdx.y == 2) ? W2 : W3;
  unsigned short* dst = Wp + (size_t)blockIdx.y * 524288;
  int l = threadIdx.x;
  int n = blockIdx.x;
  int col = 16*n + (l & 15);
  int k0 = 8 * (l >> 4);
  #pragma unroll 1
  for (int t = 0; t < 16; ++t) {
    const float* wp_ = W + (size_t)col * E_ + 32*t + k0;
    float4 a0 = *(const float4*)wp_, a1 = *(const float4*)(wp_ + 4);
    float av[8] = {a0.x,a0.y,a0.z,a0.w,a1.x,a1.y,a1.z,a1.w};
    short8 hi, lo;
    #pragma unroll
    for (int j = 0; j < 8; ++j) {
      unsigned hb = f2bf(av[j]);
      hi[j] = (short)hb;
      lo[j] = (short)f2bf(av[j] - bf2f(hb));
    }
    unsigned short* o = dst + ((size_t)(t*32 + n)*2)*512 + l*8;
    *(short8*)o = hi;
    *(short8*)(o + 512) = lo;
  }
}

// ---- hyp_linear v6: 16-wave M=32, TRUE double-buffered W staging.
// Per step: issue stage(t+1) -> buf^1; convert A + X(t+2) reg prefetch;
// 12 MFMA on buf[cur]; counted vmcnt(2) (stage drained, X in flight);
// raw s_barrier (no compiler full-drain).
template<int MODE>
__global__ __launch_bounds__(1024, 4) void hyp_linear_pack(const float* __restrict__ X,
    const unsigned short* __restrict__ Wp, const float* __restrict__ bvec,
    const float* __restrict__ xn_arr, const float* __restrict__ art_arr,
    float* __restrict__ outF, unsigned short* __restrict__ outHi,
    float* __restrict__ normOut) {
  __shared__ __align__(16) unsigned short Wt[2][32768];   // 2 x 64KB
  __shared__ float smM[8][2][4][4], smB[8][2][4][4], smb2[16];
  int tid = threadIdx.x;
  int w = tid >> 6, l = tid & 63;
  int l15 = l & 15, g = l >> 4;
  int rh = w & 1, ng = w >> 1;
  int R = blockIdx.x;                       // rows 32R .. 32R+31

  f32x4 acc[4];
  #pragma unroll
  for (int s = 0; s < 4; ++s) acc[s] = (f32x4){0.f,0.f,0.f,0.f};
  const float* xrow = X + (size_t)(R*32 + rh*16 + l15)*E_ + 8*g;

  // prologue: stage t=0 into buf0, then X(0),X(1)
  {
    const unsigned short* src = Wp + (size_t)w*512 + (size_t)l*8;
    #pragma unroll
    for (int r = 0; r < 4; ++r)
      gload_lds16(src + r*8192, &Wt[0][r*8192 + w*512]);
  }
  float4 xa0 = *(const float4*)(xrow);          // t=0
  float4 xa1 = *(const float4*)(xrow + 4);
  float4 xb0 = *(const float4*)(xrow + 32);     // t=1
  float4 xb1 = *(const float4*)(xrow + 36);
  asm volatile("s_waitcnt vmcnt(0)" ::: "memory");
  __syncthreads();

  auto step = [&](int t, float4& c0, float4& c1) {
    int cur = t & 1;
    if (t < 15) {                               // issue stage(t+1), no wait
      const unsigned short* src = Wp + (size_t)(t+1)*32768 + (size_t)w*512 + (size_t)l*8;
      #pragma unroll
      for (int r = 0; r < 4; ++r)
        gload_lds16(src + r*8192, &Wt[cur^1][r*8192 + w*512]);
    }
    __builtin_amdgcn_sched_barrier(0);          // pin: stage issues before X loads
    float av[8] = {c0.x,c0.y,c0.z,c0.w,c1.x,c1.y,c1.z,c1.w};
    short8 ahi, alo;
    #pragma unroll
    for (int j = 0; j < 8; ++j) {
      unsigned hb = f2bf(av[j]);
      ahi[j] = (short)hb;
      alo[j] = (short)f2bf(av[j] - bf2f(hb));
    }
    if (t < 14) {                               // X(t+2) reg prefetch (2 VMEM, newest)
      c0 = *(const float4*)(xrow + 32*(t+2));
      c1 = *(const float4*)(xrow + 32*(t+2) + 4);
    }
    const unsigned short* wb = &Wt[cur][(8*ng)*512] + l*8;
    #pragma unroll
    for (int s = 0; s < 4; ++s) {
      short8 bhi = *(const short8*)(wb + (2*s)*512);
      short8 blo = *(const short8*)(wb + (2*s+1)*512);
      acc[s] = __builtin_amdgcn_mfma_f32_16x16x32_bf16(ahi, bhi, acc[s], 0, 0, 0);
      acc[s] = __builtin_amdgcn_mfma_f32_16x16x32_bf16(ahi, blo, acc[s], 0, 0, 0);
      acc[s] = __builtin_amdgcn_mfma_f32_16x16x32_bf16(alo, bhi, acc[s], 0, 0, 0);
    }
    // drain stage(t+1) only; X loads (2 newest) stay in flight. vmcnt retires in order.
    if (t < 14) { asm volatile("s_waitcnt vmcnt(2)" ::: "memory"); }
    else        { asm volatile("s_waitcnt vmcnt(0)" ::: "memory"); }
    __builtin_amdgcn_s_barrier();
  };
  #pragma unroll 1
  for (int tt = 0; tt < 16; tt += 2) {
    step(tt,   xa0, xa1);
    step(tt+1, xb0, xb1);
  }

  // ---- epilogue scalars (rows rh*16 + 4g+i; cols 16*(4ng+s)+l15)
  float bl[4];
  #pragma unroll
  for (int s = 0; s < 4; ++s) bl[s] = bvec[16*(4*ng+s) + l15];
  float m2p[4] = {0.f,0.f,0.f,0.f}, mbp[4] = {0.f,0.f,0.f,0.f}, b2p = 0.f;
  #pragma unroll
  for (int s = 0; s < 4; ++s) {
    b2p += bl[s]*bl[s];
    #pragma unroll
    for (int i = 0; i < 4; ++i) {
      m2p[i] = fmaf(acc[s][i], acc[s][i], m2p[i]);
      mbp[i] = fmaf(acc[s][i], bl[s], mbp[i]);
    }
  }
  #pragma unroll
  for (int off = 1; off <= 8; off <<= 1) {
    b2p += __shfl_xor(b2p, off, 64);
    #pragma unroll
    for (int i = 0; i < 4; ++i) {
      m2p[i] += __shfl_xor(m2p[i], off, 64);
      mbp[i] += __shfl_xor(mbp[i], off, 64);
    }
  }
  __syncthreads();
  if (l == 0) smb2[w] = b2p;
  if (l15 == 0) {
    #pragma unroll
    for (int i = 0; i < 4; ++i) { smM[ng][rh][g][i] = m2p[i]; smB[ng][rh][g][i] = mbp[i]; }
  }
  __syncthreads();
  float b2 = 0.f;
  #pragma unroll
  for (int n2i = 0; n2i < 8; ++n2i) b2 += smb2[2*n2i];   // rh=0 copies
  float G[4], Hc[4];
  #pragma unroll
  for (int i = 0; i < 4; ++i) {
    float m2 = 0.f, mb = 0.f;
    #pragma unroll
    for (int n2i = 0; n2i < 8; ++n2i) { m2 += smM[n2i][rh][g][i]; mb += smB[n2i][rh][g][i]; }
    int row = R*32 + rh*16 + 4*g + i;
    float xn = xn_arr[row], art = art_arr[row];
    float mn = fmaxf(sqrtf(m2), 1e-15f);
    float t = tanhf(mn / xn * art);
    float alpha, rn;
    if (m2 > 0.f) { alpha = t / mn; rn = t; } else { alpha = 0.f; rn = 0.f; }
    if (rn > MAXN) { alpha *= MAXN / rn; rn = MAXN; }          // project(res)
    float x2r = rn * rn;
    float xy = alpha * mb;
    float A  = 1.f + 2.f*xy + b2;
    float Bc = 1.f - x2r;
    float den = fmaxf(1.f + 2.f*xy + x2r*b2, 1e-15f);
    float n2v = (A*A*x2r + 2.f*A*Bc*xy + Bc*Bc*b2) / (den*den);
    float nn = fmaxf(sqrtf(n2v), 1e-15f);
    float sc = (nn > MAXN) ? (MAXN / nn) : 1.f;                // project(add)
    G[i]  = sc * A * alpha / den;
    Hc[i] = sc * Bc / den;
  }

  // ---- outputs (head h == ng for MODE 1/2)
  #pragma unroll
  for (int i = 0; i < 4; ++i) {
    int grow = R*32 + rh*16 + 4*g + i;
    if (MODE == 3) {
      #pragma unroll
      for (int s = 0; s < 4; ++s)
        outF[(size_t)grow*E_ + 16*(4*ng+s) + l15] = G[i]*acc[s][i] + Hc[i]*bl[s];
    } else {
      int bb = grow >> 11, seq = grow & 2047;
      int tile = seq >> 6;
      float hn = 0.f;
      #pragma unroll
      for (int s = 0; s < 4; ++s) {
        int col = 16*(4*ng+s) + l15;
        float v = G[i]*acc[s][i] + Hc[i]*bl[s];
        int h = col >> 6, c = col & 63;
        size_t base;
        if (MODE == 2) {   // V layout
          int kt = (seq >> 5) & 1, gp = (seq >> 3) & 3, jv = seq & 7;
          int dn = c >> 4, lt = (c & 15) | (gp << 4);
          base = ((size_t)((bb*8 + h)*32 + tile))*4096 + (size_t)((kt*4+dn)*64 + lt)*8 + jv;
        } else {           // Q/K layout
          int nf = (seq >> 4) & 3, lt15 = seq & 15;
          int dt = c >> 5, m = (c >> 3) & 3, j = c & 7;
          base = ((size_t)((bb*8 + h)*32 + tile))*4096 + (size_t)((dt*4+nf)*64 + (lt15|(m<<4)))*8 + j;
        }
        outHi[base] = (unsigned short)f2bf(v);
        if (MODE == 1) hn += v*v;
      }
      if (MODE == 1) {
        hn += __shfl_xor(hn,1,64); hn += __shfl_xor(hn,2,64);
        hn += __shfl_xor(hn,4,64); hn += __shfl_xor(hn,8,64);
        if (l15 == 0)
          normOut[((size_t)(bb*8 + ng))*S_ + seq] = fminf(hn, 1.f - 1e-5f);
      }
    }
  }
}

// ---- Attention v8: truncated-P softmax (consistent num/den), folded constants.
__global__ __launch_bounds__(256, 4) void attn_kernel(
    const unsigned short* __restrict__ Qhi, const unsigned short* __restrict__ Khi,
    const unsigned short* __restrict__ Vhi,
    const float* __restrict__ qn_arr, const float* __restrict__ kn_arr,
    float* __restrict__ Out) {
  __shared__ __align__(16) unsigned short Kf[2][4096], Vf[2][4096];
  __shared__ __align__(16) unsigned short Pf[4][1024];

  int tid = threadIdx.x;
  int w = tid >> 6, l = tid & 63;
  int l15 = l & 15, g = l >> 4;

  int bid = blockIdx.x;                 // XCD swizzle: xcd owns bh 4*xcd..4*xcd+3
  int xcd = bid & 7, idx = bid >> 3;
  int bh = xcd * 4 + (idx >> 5);
  int qblk = idx & 31;
  int b = bh >> 3, h = bh & 7;
  int qb = qblk * 64;

  const unsigned short* qbase = Qhi + ((size_t)(bh*32 + qblk))*4096;
  short8 qhi[2];
  #pragma unroll
  for (int dt = 0; dt < 2; ++dt)
    qhi[dt] = *(const short8*)(qbase + (size_t)((dt*4 + w)*64 + l)*8);
  float qnv[4], qd[4];
  #pragma unroll
  for (int i = 0; i < 4; ++i) {
    qnv[i] = qn_arr[(size_t)bh*S_ + qb + 16*w + 4*g + i];
    qd[i] = 1.f - qnv[i];
  }

  f32x4 Oacc[4];
  #pragma unroll
  for (int dn = 0; dn < 4; ++dn) Oacc[dn] = (f32x4){0.f,0.f,0.f,0.f};
  float lp[4] = {0.f,0.f,0.f,0.f};

  const unsigned short* Kbh = Khi + ((size_t)bh*32)*4096;
  const unsigned short* Vbh = Vhi + ((size_t)bh*32)*4096;
  const float* knp = kn_arr + (size_t)bh*S_;

  // prologue: stage tile 0 via global_load_lds (verbatim linear copy)
  #pragma unroll
  for (int r = 0; r < 2; ++r) {
    gload_lds16(Kbh + r*2048 + w*512 + l*8, &Kf[0][r*2048 + w*512]);
    gload_lds16(Vbh + r*2048 + w*512 + l*8, &Vf[0][r*2048 + w*512]);
  }
  asm volatile("s_waitcnt vmcnt(0)" ::: "memory");
  __syncthreads();

  #pragma unroll 1
  for (int tile = 0; tile < 32; ++tile) {
    int cur = tile & 1;
    int kb = tile * 64;
    float knc[4];
    #pragma unroll
    for (int n = 0; n < 4; ++n) knc[n] = knp[kb + 16*n + l15];  // issue BEFORE staging
    if (tile < 31) {                    // issue stage of tile+1 into buf^1
      const unsigned short* kp = Kbh + ((size_t)(tile+1))*4096;
      const unsigned short* vp = Vbh + ((size_t)(tile+1))*4096;
      #pragma unroll
      for (int r = 0; r < 2; ++r) {
        gload_lds16(kp + r*2048 + w*512 + l*8, &Kf[cur^1][r*2048 + w*512]);
        gload_lds16(vp + r*2048 + w*512 + l*8, &Vf[cur^1][r*2048 + w*512]);
      }
    }
    // ---- QK^T + softmax + P store
    #pragma unroll
    for (int n = 0; n < 4; ++n) {
      f32x4 Cn = (f32x4){0.f,0.f,0.f,0.f};
      #pragma unroll
      for (int dt = 0; dt < 2; ++dt) {
        short8 kfr = *(const short8*)&Kf[cur][((dt*4 + n)*64 + l)*8];
        Cn = __builtin_amdgcn_mfma_f32_16x16x32_bf16(qhi[dt], kfr, Cn, 0, 0, 0);
      }
      float kd = 1.f - knc[n];
      int cbase = (n >> 1)*64 + 16*((2*n + (l15 >> 3)) & 3) + 4*g;
      int csb = cbase ^ ((cbase >> 3) & 7);      // cs_i = csb ^ i
      int j7 = l15 & 7;
      #pragma unroll
      for (int i = 0; i < 4; ++i) {
        float den = fmaf(qd[i], kd, 1e-5f);
        float r = __builtin_amdgcn_rcpf(den);
        float num = fmaf(-qnv[i], knc[n], Cn[i]);
        float d2 = fmaxf(num*r, 5e-6f);                        // = max(2nr,1e-5)/2
        float sq = d2 * __builtin_amdgcn_rsqf(d2);             // sqrt(d2)
        float p = __builtin_amdgcn_exp2f(-0.25503386f * sq);   // exp(-sqrt(2*d2)/8)
        unsigned u = __float_as_uint(p);
        lp[i] += __uint_as_float(u & 0xffff0000u);             // == stored bf16 value
        Pf[w][((csb ^ i) << 3) + j7] = (unsigned short)(u >> 16);
      }
    }
    // ---- PV
    short8 pa0, pa1;
    { int c = l;       int cs = c ^ ((c >> 3) & 7); pa0 = *(const short8*)&Pf[w][cs*8]; }
    { int c = 64 + l;  int cs = c ^ ((c >> 3) & 7); pa1 = *(const short8*)&Pf[w][cs*8]; }
    #pragma unroll
    for (int dn = 0; dn < 4; ++dn) {
      short8 v0 = *(const short8*)&Vf[cur][((0*4 + dn)*64 + l)*8];
      short8 v1 = *(const short8*)&Vf[cur][((1*4 + dn)*64 + l)*8];
      f32x4 o = Oacc[dn];
      o = __builtin_amdgcn_mfma_f32_16x16x32_bf16(pa0, v0, o, 0, 0, 0);
      o = __builtin_amdgcn_mfma_f32_16x16x32_bf16(pa1, v1, o, 0, 0, 0);
      Oacc[dn] = o;
    }
    asm volatile("s_waitcnt vmcnt(0)" ::: "memory");   // explicit staging fence
    __syncthreads();
  }

  #pragma unroll
  for (int i = 0; i < 4; ++i) {
    lp[i] += __shfl_xor(lp[i], 1, 64);
    lp[i] += __shfl_xor(lp[i], 2, 64);
    lp[i] += __shfl_xor(lp[i], 4, 64);
    lp[i] += __shfl_xor(lp[i], 8, 64);
    lp[i] = 1.f / lp[i];
  }
  #pragma unroll
  for (int i = 0; i < 4; ++i) {
    size_t orow = (size_t)(b*S_ + qb + 16*w + 4*g + i)*E_ + h*Dh_;
    #pragma unroll
    for (int dn = 0; dn < 4; ++dn)
      Out[orow + 16*dn + l15] = Oacc[dn][i] * lp[i];
  }
}

extern "C" void kernel_launch(void* const* d_in, const int* in_sizes, int n_in,
                              void* d_out, int out_size, void* d_ws, size_t ws_size,
                              hipStream_t stream) {
  const float* x  = (const float*)d_in[0];
  const float* Wq = (const float*)d_in[1];
  const float* bq = (const float*)d_in[2];
  const float* Wk = (const float*)d_in[3];
  const float* bk = (const float*)d_in[4];
  const float* Wv = (const float*)d_in[5];
  const float* bv = (const float*)d_in[6];
  const float* Wo = (const float*)d_in[7];
  const float* bo = (const float*)d_in[8];
  float* out = (float*)d_out;

  char* p = (char*)d_ws;
  unsigned short* Wp  = (unsigned short*)p; p += (size_t)4  << 20;  // 4 MB
  unsigned short* Qhi = (unsigned short*)p; p += (size_t)8  << 20;
  unsigned short* Khi = (unsigned short*)p; p += (size_t)8  << 20;
  unsigned short* Vhi = (unsigned short*)p; p += (size_t)8  << 20;
  float* ao   = (float*)p; p += (size_t)16 << 20;                   // attn out fp32
  float* xn   = (float*)p; p += BS_ * 4;
  float* art  = (float*)p; p += BS_ * 4;
  float* xn2  = (float*)p; p += BS_ * 4;
  float* art2 = (float*)p; p += BS_ * 4;
  float* qn   = (float*)p; p += (size_t)B_*H_*S_ * 4;
  float* kn   = (float*)p; p += (size_t)B_*H_*S_ * 4;
  // total ~= 44.6 MB

  pack_w_kernel<<<dim3(32, 4), dim3(64), 0, stream>>>(Wq, Wk, Wv, Wo, Wp);
  row_stats_kernel<<<dim3(BS_/4), dim3(256), 0, stream>>>(x, xn, art);
  hyp_linear_pack<1><<<dim3(BS_/32), dim3(1024), 0, stream>>>(x, Wp,            bq, xn, art, nullptr, Qhi, qn);
  hyp_linear_pack<1><<<dim3(BS_/32), dim3(1024), 0, stream>>>(x, Wp + 524288,   bk, xn, art, nullptr, Khi, kn);
  hyp_linear_pack<2><<<dim3(BS_/32), dim3(1024), 0, stream>>>(x, Wp + 2*524288, bv, xn, art, nullptr, Vhi, nullptr);
  attn_kernel<<<dim3(1024), dim3(256), 0, stream>>>(Qhi, Khi, Vhi, qn, kn, ao);
  row_stats_kernel<<<dim3(BS_/4), dim3(256), 0, stream>>>(ao, xn2, art2);
  hyp_linear_pack<3><<<dim3(BS_/32), dim3(1024), 0, stream>>>(ao, Wp + 3*524288, bo, xn2, art2, out, nullptr, nullptr);
}

// Round 11
// 229.013 us; speedup vs baseline: 1.2226x; 1.1331x over previous
//
#include <hip/hip_runtime.h>
#include <math.h>

#define B_ 4
#define S_ 2048
#define E_ 512
#define H_ 8
#define Dh_ 64
#define BS_ (B_*S_)
#define MAXN 0.996f   // (1 - 4e-3)/sqrt(c), c=1

typedef __attribute__((ext_vector_type(8))) short short8;
typedef __attribute__((ext_vector_type(4))) float f32x4;

__device__ __forceinline__ unsigned f2bf(float x) {            // RNE f32->bf16 bits
  unsigned u = __float_as_uint(x);
  return (u + 0x7fffu + ((u >> 16) & 1u)) >> 16;
}
__device__ __forceinline__ float bf2f(unsigned b) {
  return __uint_as_float(b << 16);
}

__device__ __forceinline__ void gload_lds16(const void* g, void* lds) {
  __builtin_amdgcn_global_load_lds(
      (const __attribute__((address_space(1))) unsigned int*)g,
      (__attribute__((address_space(3))) unsigned int*)lds, 16, 0, 0);
}

// ---- pack W matrices: t-major B-frag order (contiguous 64KB per K-step)
// Wp[mat][ ((t*32 + n)*2 + hl)*512 + l*8 + j ]
// element: W[16n + (l&15)][32t + 8*(l>>4) + j]
__global__ __launch_bounds__(256) void pack_w_kernel(const float* __restrict__ W0,
    const float* __restrict__ W1, const float* __restrict__ W2,
    const float* __restrict__ W3, unsigned short* __restrict__ Wp) {
  const float* W = (blockIdx.y == 0) ? W0 : (blockIdx.y == 1) ? W1
                 : (blockIdx.y == 2) ? W2 : W3;
  unsigned short* dst = Wp + (size_t)blockIdx.y * 524288;
  int l = threadIdx.x & 63, tq = threadIdx.x >> 6;
  int n = blockIdx.x;
  int col = 16*n + (l & 15);
  int k0 = 8 * (l >> 4);
  #pragma unroll
  for (int tt = 0; tt < 4; ++tt) {
    int t = tq*4 + tt;
    const float* wp_ = W + (size_t)col * E_ + 32*t + k0;
    float4 a0 = *(const float4*)wp_, a1 = *(const float4*)(wp_ + 4);
    float av[8] = {a0.x,a0.y,a0.z,a0.w,a1.x,a1.y,a1.z,a1.w};
    short8 hi, lo;
    #pragma unroll
    for (int j = 0; j < 8; ++j) {
      unsigned hb = f2bf(av[j]);
      hi[j] = (short)hb;
      lo[j] = (short)f2bf(av[j] - bf2f(hb));
    }
    unsigned short* o = dst + ((size_t)(t*32 + n)*2)*512 + l*8;
    *(short8*)o = hi;
    *(short8*)(o + 512) = lo;
  }
}

// ---- fused QKV: 16 waves, M=32, shared X/A-fragments, 3-matrix round-robin
// double-buffer. Wave w: rh=w&1 (row half), ng=w>>1 (head = n-tiles 4ng..4ng+3).
// Inline row-stats (xn/art) accumulated during A-convert.
__global__ __launch_bounds__(1024, 4) void fused_qkv(const float* __restrict__ X,
    const unsigned short* __restrict__ Wp,
    const float* __restrict__ bq_, const float* __restrict__ bk_,
    const float* __restrict__ bv_,
    unsigned short* __restrict__ Qhi, unsigned short* __restrict__ Khi,
    unsigned short* __restrict__ Vhi,
    float* __restrict__ qn, float* __restrict__ kn) {
  __shared__ __align__(16) unsigned short Wt[2][32768];   // 2 x 64KB
  __shared__ float smM[8][2][4][4], smB[8][2][4][4], smb2[16];
  int tid = threadIdx.x;
  int w = tid >> 6, l = tid & 63;
  int l15 = l & 15, g = l >> 4;
  int rh = w & 1, ng = w >> 1;
  int R = blockIdx.x;                       // rows 32R .. 32R+31

  const unsigned short* WpQ = Wp;
  const unsigned short* WpK = Wp + 524288;
  const unsigned short* WpV = Wp + 1048576;

  f32x4 accQ[4], accK[4], accV[4];
  #pragma unroll
  for (int s = 0; s < 4; ++s) {
    accQ[s] = (f32x4){0.f,0.f,0.f,0.f};
    accK[s] = (f32x4){0.f,0.f,0.f,0.f};
    accV[s] = (f32x4){0.f,0.f,0.f,0.f};
  }
  const float* xrow = X + (size_t)(R*32 + rh*16 + l15)*E_ + 8*g;

  // prologue: stage (t0,Q) into buf0; X(0)
  {
    const unsigned short* src = WpQ + (size_t)w*512 + (size_t)l*8;
    #pragma unroll
    for (int r = 0; r < 4; ++r)
      gload_lds16(src + r*8192, &Wt[0][r*8192 + w*512]);
  }
  float4 c0 = *(const float4*)xrow;
  float4 c1 = *(const float4*)(xrow + 4);
  asm volatile("s_waitcnt vmcnt(0)" ::: "memory");
  __syncthreads();

  float xsq = 0.f;

  #pragma unroll 1
  for (int t = 0; t < 16; ++t) {
    int p0 = t & 1;
    short8 ahi, alo;
    // ---- Q vstep: compute Wt[p0], stage K(t) -> Wt[p0^1]
    {
      float av[8] = {c0.x,c0.y,c0.z,c0.w,c1.x,c1.y,c1.z,c1.w};
      #pragma unroll
      for (int j = 0; j < 8; ++j) {
        unsigned hb = f2bf(av[j]);
        ahi[j] = (short)hb;
        alo[j] = (short)f2bf(av[j] - bf2f(hb));
        xsq = fmaf(av[j], av[j], xsq);
      }
      const unsigned short* src = WpK + (size_t)t*32768 + (size_t)w*512 + (size_t)l*8;
      #pragma unroll
      for (int r = 0; r < 4; ++r)
        gload_lds16(src + r*8192, &Wt[p0^1][r*8192 + w*512]);
      __builtin_amdgcn_sched_barrier(0);
      const unsigned short* wb = &Wt[p0][(8*ng)*512] + l*8;
      #pragma unroll
      for (int s = 0; s < 4; ++s) {
        short8 bhi = *(const short8*)(wb + (2*s)*512);
        short8 blo = *(const short8*)(wb + (2*s+1)*512);
        accQ[s] = __builtin_amdgcn_mfma_f32_16x16x32_bf16(ahi, bhi, accQ[s], 0, 0, 0);
        accQ[s] = __builtin_amdgcn_mfma_f32_16x16x32_bf16(ahi, blo, accQ[s], 0, 0, 0);
        accQ[s] = __builtin_amdgcn_mfma_f32_16x16x32_bf16(alo, bhi, accQ[s], 0, 0, 0);
      }
      asm volatile("s_waitcnt vmcnt(0)" ::: "memory");
      __builtin_amdgcn_s_barrier();
    }
    // ---- K vstep: compute Wt[p0^1], stage V(t) -> Wt[p0]; X(t+1) prefetch (newest)
    {
      const unsigned short* src = WpV + (size_t)t*32768 + (size_t)w*512 + (size_t)l*8;
      #pragma unroll
      for (int r = 0; r < 4; ++r)
        gload_lds16(src + r*8192, &Wt[p0][r*8192 + w*512]);
      __builtin_amdgcn_sched_barrier(0);
      if (t < 15) {
        c0 = *(const float4*)(xrow + 32*(t+1));
        c1 = *(const float4*)(xrow + 32*(t+1) + 4);
      }
      const unsigned short* wb = &Wt[p0^1][(8*ng)*512] + l*8;
      #pragma unroll
      for (int s = 0; s < 4; ++s) {
        short8 bhi = *(const short8*)(wb + (2*s)*512);
        short8 blo = *(const short8*)(wb + (2*s+1)*512);
        accK[s] = __builtin_amdgcn_mfma_f32_16x16x32_bf16(ahi, bhi, accK[s], 0, 0, 0);
        accK[s] = __builtin_amdgcn_mfma_f32_16x16x32_bf16(ahi, blo, accK[s], 0, 0, 0);
        accK[s] = __builtin_amdgcn_mfma_f32_16x16x32_bf16(alo, bhi, accK[s], 0, 0, 0);
      }
      // drain stage(V) = oldest 4; X loads (2 newest) stay in flight
      if (t < 15) { asm volatile("s_waitcnt vmcnt(2)" ::: "memory"); }
      else        { asm volatile("s_waitcnt vmcnt(0)" ::: "memory"); }
      __builtin_amdgcn_s_barrier();
    }
    // ---- V vstep: compute Wt[p0], stage Q(t+1) -> Wt[p0^1]
    {
      if (t < 15) {
        const unsigned short* src = WpQ + (size_t)(t+1)*32768 + (size_t)w*512 + (size_t)l*8;
        #pragma unroll
        for (int r = 0; r < 4; ++r)
          gload_lds16(src + r*8192, &Wt[p0^1][r*8192 + w*512]);
      }
      __builtin_amdgcn_sched_barrier(0);
      const unsigned short* wb = &Wt[p0][(8*ng)*512] + l*8;
      #pragma unroll
      for (int s = 0; s < 4; ++s) {
        short8 bhi = *(const short8*)(wb + (2*s)*512);
        short8 blo = *(const short8*)(wb + (2*s+1)*512);
        accV[s] = __builtin_amdgcn_mfma_f32_16x16x32_bf16(ahi, bhi, accV[s], 0, 0, 0);
        accV[s] = __builtin_amdgcn_mfma_f32_16x16x32_bf16(ahi, blo, accV[s], 0, 0, 0);
        accV[s] = __builtin_amdgcn_mfma_f32_16x16x32_bf16(alo, bhi, accV[s], 0, 0, 0);
      }
      asm volatile("s_waitcnt vmcnt(0)" ::: "memory");
      __builtin_amdgcn_s_barrier();
    }
  }

  // ---- inline row-stats: full ||x_row||^2 then artanh per C-row
  xsq += __shfl_xor(xsq, 16, 64);
  xsq += __shfl_xor(xsq, 32, 64);
  float xnv4[4], art4[4];
  #pragma unroll
  for (int i = 0; i < 4; ++i) {
    float s2 = __shfl(xsq, 4*g + i, 64);
    float xnv = fmaxf(sqrtf(s2), 1e-15f);
    float aa = fminf(xnv, 1.f - 1e-7f);
    xnv4[i] = xnv;
    art4[i] = 0.5f * (log1pf(aa) - log1pf(-aa));
  }

  // ---- per-matrix Mobius epilogue + packed store
  auto epi = [&](const f32x4* acc, const float* bvec, int mode,
                 unsigned short* outHi, float* normOut) {
    float bl[4];
    #pragma unroll
    for (int s = 0; s < 4; ++s) bl[s] = bvec[16*(4*ng+s) + l15];
    float m2p[4] = {0.f,0.f,0.f,0.f}, mbp[4] = {0.f,0.f,0.f,0.f}, b2p = 0.f;
    #pragma unroll
    for (int s = 0; s < 4; ++s) {
      b2p += bl[s]*bl[s];
      #pragma unroll
      for (int i = 0; i < 4; ++i) {
        m2p[i] = fmaf(acc[s][i], acc[s][i], m2p[i]);
        mbp[i] = fmaf(acc[s][i], bl[s], mbp[i]);
      }
    }
    #pragma unroll
    for (int off = 1; off <= 8; off <<= 1) {
      b2p += __shfl_xor(b2p, off, 64);
      #pragma unroll
      for (int i = 0; i < 4; ++i) {
        m2p[i] += __shfl_xor(m2p[i], off, 64);
        mbp[i] += __shfl_xor(mbp[i], off, 64);
      }
    }
    __syncthreads();                      // previous matrix's smM reads done
    if (l == 0) smb2[w] = b2p;
    if (l15 == 0) {
      #pragma unroll
      for (int i = 0; i < 4; ++i) { smM[ng][rh][g][i] = m2p[i]; smB[ng][rh][g][i] = mbp[i]; }
    }
    __syncthreads();
    float b2 = 0.f;
    #pragma unroll
    for (int q = 0; q < 8; ++q) b2 += smb2[2*q];
    float G[4], Hc[4];
    #pragma unroll
    for (int i = 0; i < 4; ++i) {
      float m2 = 0.f, mb = 0.f;
      #pragma unroll
      for (int q = 0; q < 8; ++q) { m2 += smM[q][rh][g][i]; mb += smB[q][rh][g][i]; }
      float xn = xnv4[i], art = art4[i];
      float mn = fmaxf(sqrtf(m2), 1e-15f);
      float t = tanhf(mn / xn * art);
      float alpha, rn;
      if (m2 > 0.f) { alpha = t / mn; rn = t; } else { alpha = 0.f; rn = 0.f; }
      if (rn > MAXN) { alpha *= MAXN / rn; rn = MAXN; }        // project(res)
      float x2r = rn * rn;
      float xy = alpha * mb;
      float A  = 1.f + 2.f*xy + b2;
      float Bc = 1.f - x2r;
      float den = fmaxf(1.f + 2.f*xy + x2r*b2, 1e-15f);
      float n2v = (A*A*x2r + 2.f*A*Bc*xy + Bc*Bc*b2) / (den*den);
      float nn = fmaxf(sqrtf(n2v), 1e-15f);
      float sc = (nn > MAXN) ? (MAXN / nn) : 1.f;              // project(add)
      G[i]  = sc * A * alpha / den;
      Hc[i] = sc * Bc / den;
    }
    #pragma unroll
    for (int i = 0; i < 4; ++i) {
      int grow = R*32 + rh*16 + 4*g + i;
      int bb = grow >> 11, seq = grow & 2047;
      int tile = seq >> 6;
      float hn = 0.f;
      #pragma unroll
      for (int s = 0; s < 4; ++s) {
        int col = 16*(4*ng+s) + l15;
        float v = G[i]*acc[s][i] + Hc[i]*bl[s];
        int h = col >> 6, c = col & 63;
        size_t base;
        if (mode == 2) {   // V layout
          int kt = (seq >> 5) & 1, gp = (seq >> 3) & 3, jv = seq & 7;
          int dn = c >> 4, lt = (c & 15) | (gp << 4);
          base = ((size_t)((bb*8 + h)*32 + tile))*4096 + (size_t)((kt*4+dn)*64 + lt)*8 + jv;
        } else {           // Q/K layout
          int nf = (seq >> 4) & 3, lt15 = seq & 15;
          int dt = c >> 5, m = (c >> 3) & 3, j = c & 7;
          base = ((size_t)((bb*8 + h)*32 + tile))*4096 + (size_t)((dt*4+nf)*64 + (lt15|(m<<4)))*8 + j;
        }
        outHi[base] = (unsigned short)f2bf(v);
        if (mode == 1) hn += v*v;
      }
      if (mode == 1) {
        hn += __shfl_xor(hn,1,64); hn += __shfl_xor(hn,2,64);
        hn += __shfl_xor(hn,4,64); hn += __shfl_xor(hn,8,64);
        if (l15 == 0)
          normOut[((size_t)(bb*8 + ng))*S_ + seq] = fminf(hn, 1.f - 1e-5f);
      }
    }
  };
  epi(accQ, bq_, 1, Qhi, qn);
  epi(accK, bk_, 1, Khi, kn);
  epi(accV, bv_, 2, Vhi, nullptr);
}

// ---- fused O-linear: r9 double-buffered structure + inline row-stats of ao.
__global__ __launch_bounds__(1024, 4) void fused_o(const float* __restrict__ X,
    const unsigned short* __restrict__ Wp, const float* __restrict__ bvec,
    float* __restrict__ outF) {
  __shared__ __align__(16) unsigned short Wt[2][32768];
  __shared__ float smM[8][2][4][4], smB[8][2][4][4], smb2[16];
  int tid = threadIdx.x;
  int w = tid >> 6, l = tid & 63;
  int l15 = l & 15, g = l >> 4;
  int rh = w & 1, ng = w >> 1;
  int R = blockIdx.x;

  f32x4 acc[4];
  #pragma unroll
  for (int s = 0; s < 4; ++s) acc[s] = (f32x4){0.f,0.f,0.f,0.f};
  const float* xrow = X + (size_t)(R*32 + rh*16 + l15)*E_ + 8*g;

  {
    const unsigned short* src = Wp + (size_t)w*512 + (size_t)l*8;
    #pragma unroll
    for (int r = 0; r < 4; ++r)
      gload_lds16(src + r*8192, &Wt[0][r*8192 + w*512]);
  }
  float4 xa0 = *(const float4*)(xrow);
  float4 xa1 = *(const float4*)(xrow + 4);
  float4 xb0 = *(const float4*)(xrow + 32);
  float4 xb1 = *(const float4*)(xrow + 36);
  asm volatile("s_waitcnt vmcnt(0)" ::: "memory");
  __syncthreads();

  float xsq = 0.f;
  auto step = [&](int t, float4& c0, float4& c1) {
    int cur = t & 1;
    if (t < 15) {
      const unsigned short* src = Wp + (size_t)(t+1)*32768 + (size_t)w*512 + (size_t)l*8;
      #pragma unroll
      for (int r = 0; r < 4; ++r)
        gload_lds16(src + r*8192, &Wt[cur^1][r*8192 + w*512]);
    }
    __builtin_amdgcn_sched_barrier(0);
    float av[8] = {c0.x,c0.y,c0.z,c0.w,c1.x,c1.y,c1.z,c1.w};
    short8 ahi, alo;
    #pragma unroll
    for (int j = 0; j < 8; ++j) {
      unsigned hb = f2bf(av[j]);
      ahi[j] = (short)hb;
      alo[j] = (short)f2bf(av[j] - bf2f(hb));
      xsq = fmaf(av[j], av[j], xsq);
    }
    if (t < 14) {
      c0 = *(const float4*)(xrow + 32*(t+2));
      c1 = *(const float4*)(xrow + 32*(t+2) + 4);
    }
    const unsigned short* wb = &Wt[cur][(8*ng)*512] + l*8;
    #pragma unroll
    for (int s = 0; s < 4; ++s) {
      short8 bhi = *(const short8*)(wb + (2*s)*512);
      short8 blo = *(const short8*)(wb + (2*s+1)*512);
      acc[s] = __builtin_amdgcn_mfma_f32_16x16x32_bf16(ahi, bhi, acc[s], 0, 0, 0);
      acc[s] = __builtin_amdgcn_mfma_f32_16x16x32_bf16(ahi, blo, acc[s], 0, 0, 0);
      acc[s] = __builtin_amdgcn_mfma_f32_16x16x32_bf16(alo, bhi, acc[s], 0, 0, 0);
    }
    if (t < 14) { asm volatile("s_waitcnt vmcnt(2)" ::: "memory"); }
    else        { asm volatile("s_waitcnt vmcnt(0)" ::: "memory"); }
    __builtin_amdgcn_s_barrier();
  };
  #pragma unroll 1
  for (int tt = 0; tt < 16; tt += 2) {
    step(tt,   xa0, xa1);
    step(tt+1, xb0, xb1);
  }

  xsq += __shfl_xor(xsq, 16, 64);
  xsq += __shfl_xor(xsq, 32, 64);
  float xnv4[4], art4[4];
  #pragma unroll
  for (int i = 0; i < 4; ++i) {
    float s2 = __shfl(xsq, 4*g + i, 64);
    float xnv = fmaxf(sqrtf(s2), 1e-15f);
    float aa = fminf(xnv, 1.f - 1e-7f);
    xnv4[i] = xnv;
    art4[i] = 0.5f * (log1pf(aa) - log1pf(-aa));
  }

  float bl[4];
  #pragma unroll
  for (int s = 0; s < 4; ++s) bl[s] = bvec[16*(4*ng+s) + l15];
  float m2p[4] = {0.f,0.f,0.f,0.f}, mbp[4] = {0.f,0.f,0.f,0.f}, b2p = 0.f;
  #pragma unroll
  for (int s = 0; s < 4; ++s) {
    b2p += bl[s]*bl[s];
    #pragma unroll
    for (int i = 0; i < 4; ++i) {
      m2p[i] = fmaf(acc[s][i], acc[s][i], m2p[i]);
      mbp[i] = fmaf(acc[s][i], bl[s], mbp[i]);
    }
  }
  #pragma unroll
  for (int off = 1; off <= 8; off <<= 1) {
    b2p += __shfl_xor(b2p, off, 64);
    #pragma unroll
    for (int i = 0; i < 4; ++i) {
      m2p[i] += __shfl_xor(m2p[i], off, 64);
      mbp[i] += __shfl_xor(mbp[i], off, 64);
    }
  }
  __syncthreads();
  if (l == 0) smb2[w] = b2p;
  if (l15 == 0) {
    #pragma unroll
    for (int i = 0; i < 4; ++i) { smM[ng][rh][g][i] = m2p[i]; smB[ng][rh][g][i] = mbp[i]; }
  }
  __syncthreads();
  float b2 = 0.f;
  #pragma unroll
  for (int q = 0; q < 8; ++q) b2 += smb2[2*q];
  #pragma unroll
  for (int i = 0; i < 4; ++i) {
    float m2 = 0.f, mb = 0.f;
    #pragma unroll
    for (int q = 0; q < 8; ++q) { m2 += smM[q][rh][g][i]; mb += smB[q][rh][g][i]; }
    float xn = xnv4[i], art = art4[i];
    float mn = fmaxf(sqrtf(m2), 1e-15f);
    float t = tanhf(mn / xn * art);
    float alpha, rn;
    if (m2 > 0.f) { alpha = t / mn; rn = t; } else { alpha = 0.f; rn = 0.f; }
    if (rn > MAXN) { alpha *= MAXN / rn; rn = MAXN; }
    float x2r = rn * rn;
    float xy = alpha * mb;
    float A  = 1.f + 2.f*xy + b2;
    float Bc = 1.f - x2r;
    float den = fmaxf(1.f + 2.f*xy + x2r*b2, 1e-15f);
    float n2v = (A*A*x2r + 2.f*A*Bc*xy + Bc*Bc*b2) / (den*den);
    float nn = fmaxf(sqrtf(n2v), 1e-15f);
    float sc = (nn > MAXN) ? (MAXN / nn) : 1.f;
    float G = sc * A * alpha / den;
    float Hc = sc * Bc / den;
    int grow = R*32 + rh*16 + 4*g + i;
    #pragma unroll
    for (int s = 0; s < 4; ++s)
      outF[(size_t)grow*E_ + 16*(4*ng+s) + l15] = G*acc[s][i] + Hc*bl[s];
  }
}

// ---- Attention (r9-proven)
__global__ __launch_bounds__(256, 4) void attn_kernel(
    const unsigned short* __restrict__ Qhi, const unsigned short* __restrict__ Khi,
    const unsigned short* __restrict__ Vhi,
    const float* __restrict__ qn_arr, const float* __restrict__ kn_arr,
    float* __restrict__ Out) {
  __shared__ __align__(16) unsigned short Kf[2][4096], Vf[2][4096];
  __shared__ __align__(16) unsigned short Pf[4][1024];

  int tid = threadIdx.x;
  int w = tid >> 6, l = tid & 63;
  int l15 = l & 15, g = l >> 4;

  int bid = blockIdx.x;                 // XCD swizzle: xcd owns bh 4*xcd..4*xcd+3
  int xcd = bid & 7, idx = bid >> 3;
  int bh = xcd * 4 + (idx >> 5);
  int qblk = idx & 31;
  int b = bh >> 3, h = bh & 7;
  int qb = qblk * 64;

  const unsigned short* qbase = Qhi + ((size_t)(bh*32 + qblk))*4096;
  short8 qhi[2];
  #pragma unroll
  for (int dt = 0; dt < 2; ++dt)
    qhi[dt] = *(const short8*)(qbase + (size_t)((dt*4 + w)*64 + l)*8);
  float qnv[4], qd[4];
  #pragma unroll
  for (int i = 0; i < 4; ++i) {
    qnv[i] = qn_arr[(size_t)bh*S_ + qb + 16*w + 4*g + i];
    qd[i] = 1.f - qnv[i];
  }

  f32x4 Oacc[4];
  #pragma unroll
  for (int dn = 0; dn < 4; ++dn) Oacc[dn] = (f32x4){0.f,0.f,0.f,0.f};
  float lp[4] = {0.f,0.f,0.f,0.f};

  const unsigned short* Kbh = Khi + ((size_t)bh*32)*4096;
  const unsigned short* Vbh = Vhi + ((size_t)bh*32)*4096;
  const float* knp = kn_arr + (size_t)bh*S_;

  #pragma unroll
  for (int r = 0; r < 2; ++r) {
    gload_lds16(Kbh + r*2048 + w*512 + l*8, &Kf[0][r*2048 + w*512]);
    gload_lds16(Vbh + r*2048 + w*512 + l*8, &Vf[0][r*2048 + w*512]);
  }
  asm volatile("s_waitcnt vmcnt(0)" ::: "memory");
  __syncthreads();

  #pragma unroll 1
  for (int tile = 0; tile < 32; ++tile) {
    int cur = tile & 1;
    int kb = tile * 64;
    float knc[4];
    #pragma unroll
    for (int n = 0; n < 4; ++n) knc[n] = knp[kb + 16*n + l15];  // issue BEFORE staging
    if (tile < 31) {
      const unsigned short* kp = Kbh + ((size_t)(tile+1))*4096;
      const unsigned short* vp = Vbh + ((size_t)(tile+1))*4096;
      #pragma unroll
      for (int r = 0; r < 2; ++r) {
        gload_lds16(kp + r*2048 + w*512 + l*8, &Kf[cur^1][r*2048 + w*512]);
        gload_lds16(vp + r*2048 + w*512 + l*8, &Vf[cur^1][r*2048 + w*512]);
      }
    }
    // ---- QK^T + softmax + P store
    #pragma unroll
    for (int n = 0; n < 4; ++n) {
      f32x4 Cn = (f32x4){0.f,0.f,0.f,0.f};
      #pragma unroll
      for (int dt = 0; dt < 2; ++dt) {
        short8 kfr = *(const short8*)&Kf[cur][((dt*4 + n)*64 + l)*8];
        Cn = __builtin_amdgcn_mfma_f32_16x16x32_bf16(qhi[dt], kfr, Cn, 0, 0, 0);
      }
      float kd = 1.f - knc[n];
      int cbase = (n >> 1)*64 + 16*((2*n + (l15 >> 3)) & 3) + 4*g;
      int csb = cbase ^ ((cbase >> 3) & 7);      // cs_i = csb ^ i
      int j7 = l15 & 7;
      #pragma unroll
      for (int i = 0; i < 4; ++i) {
        float den = fmaf(qd[i], kd, 1e-5f);
        float r = __builtin_amdgcn_rcpf(den);
        float num = fmaf(-qnv[i], knc[n], Cn[i]);
        float d2 = fmaxf(num*r, 5e-6f);                        // = max(2nr,1e-5)/2
        float sq = d2 * __builtin_amdgcn_rsqf(d2);             // sqrt(d2)
        float p = __builtin_amdgcn_exp2f(-0.25503386f * sq);   // exp(-sqrt(2*d2)/8)
        unsigned u = __float_as_uint(p);
        lp[i] += __uint_as_float(u & 0xffff0000u);             // == stored bf16 value
        Pf[w][((csb ^ i) << 3) + j7] = (unsigned short)(u >> 16);
      }
    }
    // ---- PV
    short8 pa0, pa1;
    { int c = l;       int cs = c ^ ((c >> 3) & 7); pa0 = *(const short8*)&Pf[w][cs*8]; }
    { int c = 64 + l;  int cs = c ^ ((c >> 3) & 7); pa1 = *(const short8*)&Pf[w][cs*8]; }
    #pragma unroll
    for (int dn = 0; dn < 4; ++dn) {
      short8 v0 = *(const short8*)&Vf[cur][((0*4 + dn)*64 + l)*8];
      short8 v1 = *(const short8*)&Vf[cur][((1*4 + dn)*64 + l)*8];
      f32x4 o = Oacc[dn];
      o = __builtin_amdgcn_mfma_f32_16x16x32_bf16(pa0, v0, o, 0, 0, 0);
      o = __builtin_amdgcn_mfma_f32_16x16x32_bf16(pa1, v1, o, 0, 0, 0);
      Oacc[dn] = o;
    }
    asm volatile("s_waitcnt vmcnt(0)" ::: "memory");
    __syncthreads();
  }

  #pragma unroll
  for (int i = 0; i < 4; ++i) {
    lp[i] += __shfl_xor(lp[i], 1, 64);
    lp[i] += __shfl_xor(lp[i], 2, 64);
    lp[i] += __shfl_xor(lp[i], 4, 64);
    lp[i] += __shfl_xor(lp[i], 8, 64);
    lp[i] = 1.f / lp[i];
  }
  #pragma unroll
  for (int i = 0; i < 4; ++i) {
    size_t orow = (size_t)(b*S_ + qb + 16*w + 4*g + i)*E_ + h*Dh_;
    #pragma unroll
    for (int dn = 0; dn < 4; ++dn)
      Out[orow + 16*dn + l15] = Oacc[dn][i] * lp[i];
  }
}

extern "C" void kernel_launch(void* const* d_in, const int* in_sizes, int n_in,
                              void* d_out, int out_size, void* d_ws, size_t ws_size,
                              hipStream_t stream) {
  const float* x  = (const float*)d_in[0];
  const float* Wq = (const float*)d_in[1];
  const float* bq = (const float*)d_in[2];
  const float* Wk = (const float*)d_in[3];
  const float* bk = (const float*)d_in[4];
  const float* Wv = (const float*)d_in[5];
  const float* bv = (const float*)d_in[6];
  const float* Wo = (const float*)d_in[7];
  const float* bo = (const float*)d_in[8];
  float* out = (float*)d_out;

  char* p = (char*)d_ws;
  unsigned short* Wp  = (unsigned short*)p; p += (size_t)4  << 20;  // 4 MB
  unsigned short* Qhi = (unsigned short*)p; p += (size_t)8  << 20;
  unsigned short* Khi = (unsigned short*)p; p += (size_t)8  << 20;
  unsigned short* Vhi = (unsigned short*)p; p += (size_t)8  << 20;
  float* ao   = (float*)p; p += (size_t)16 << 20;                   // attn out fp32
  float* qn   = (float*)p; p += (size_t)B_*H_*S_ * 4;
  float* kn   = (float*)p; p += (size_t)B_*H_*S_ * 4;
  // total ~= 44.5 MB

  pack_w_kernel<<<dim3(32, 4), dim3(256), 0, stream>>>(Wq, Wk, Wv, Wo, Wp);
  fused_qkv<<<dim3(BS_/32), dim3(1024), 0, stream>>>(x, Wp, bq, bk, bv, Qhi, Khi, Vhi, qn, kn);
  attn_kernel<<<dim3(1024), dim3(256), 0, stream>>>(Qhi, Khi, Vhi, qn, kn, ao);
  fused_o<<<dim3(BS_/32), dim3(1024), 0, stream>>>(ao, Wp + 3*524288, bo, out);
}

// Round 12
// 199.414 us; speedup vs baseline: 1.4041x; 1.1484x over previous
//
#include <hip/hip_runtime.h>
#include <math.h>

#define B_ 4
#define S_ 2048
#define E_ 512
#define H_ 8
#define Dh_ 64
#define BS_ (B_*S_)
#define MAXN 0.996f   // (1 - 4e-3)/sqrt(c), c=1

typedef __attribute__((ext_vector_type(8))) short short8;
typedef __attribute__((ext_vector_type(4))) float f32x4;

__device__ __forceinline__ unsigned f2bf(float x) {            // RNE f32->bf16 bits
  unsigned u = __float_as_uint(x);
  return (u + 0x7fffu + ((u >> 16) & 1u)) >> 16;
}
__device__ __forceinline__ float bf2f(unsigned b) {
  return __uint_as_float(b << 16);
}

__device__ __forceinline__ void gload_lds16(const void* g, void* lds) {
  __builtin_amdgcn_global_load_lds(
      (const __attribute__((address_space(1))) unsigned int*)g,
      (__attribute__((address_space(3))) unsigned int*)lds, 16, 0, 0);
}

// ---- pack W matrices: t-major B-frag order, HI ONLY (32KB per K-step slice)
// Wp[mat][ (t*32 + n)*512 + l*8 + j ]
// element: W[16n + (l&15)][32t + 8*(l>>4) + j]
__global__ __launch_bounds__(256) void pack_w_kernel(const float* __restrict__ W0,
    const float* __restrict__ W1, const float* __restrict__ W2,
    const float* __restrict__ W3, unsigned short* __restrict__ Wp) {
  const float* W = (blockIdx.y == 0) ? W0 : (blockIdx.y == 1) ? W1
                 : (blockIdx.y == 2) ? W2 : W3;
  unsigned short* dst = Wp + (size_t)blockIdx.y * 262144;
  int l = threadIdx.x & 63, tq = threadIdx.x >> 6;
  int n = blockIdx.x;
  int col = 16*n + (l & 15);
  int k0 = 8 * (l >> 4);
  #pragma unroll
  for (int tt = 0; tt < 4; ++tt) {
    int t = tq*4 + tt;
    const float* wp_ = W + (size_t)col * E_ + 32*t + k0;
    float4 a0 = *(const float4*)wp_, a1 = *(const float4*)(wp_ + 4);
    float av[8] = {a0.x,a0.y,a0.z,a0.w,a1.x,a1.y,a1.z,a1.w};
    short8 hi;
    #pragma unroll
    for (int j = 0; j < 8; ++j) hi[j] = (short)f2bf(av[j]);
    *(short8*)(dst + ((size_t)(t*32 + n))*512 + l*8) = hi;
  }
}

// ---- fused QKV: 16 waves, M=32, W hi-only (2 MFMA/step: ahi*bhi + alo*bhi).
// 3-matrix round-robin through 2 x 32KB LDS buffers. Inline row-stats.
__global__ __launch_bounds__(1024, 4) void fused_qkv(const float* __restrict__ X,
    const unsigned short* __restrict__ Wp,
    const float* __restrict__ bq_, const float* __restrict__ bk_,
    const float* __restrict__ bv_,
    unsigned short* __restrict__ Qhi, unsigned short* __restrict__ Khi,
    unsigned short* __restrict__ Vhi,
    float* __restrict__ qn, float* __restrict__ kn) {
  __shared__ __align__(16) unsigned short Wt[2][16384];   // 2 x 32KB
  __shared__ float smM[8][2][4][4], smB[8][2][4][4], smb2[16];
  int tid = threadIdx.x;
  int w = tid >> 6, l = tid & 63;
  int l15 = l & 15, g = l >> 4;
  int rh = w & 1, ng = w >> 1;
  int R = blockIdx.x;                       // rows 32R .. 32R+31

  const unsigned short* WpQ = Wp;
  const unsigned short* WpK = Wp + 262144;
  const unsigned short* WpV = Wp + 524288;

  f32x4 accQ[4], accK[4], accV[4];
  #pragma unroll
  for (int s = 0; s < 4; ++s) {
    accQ[s] = (f32x4){0.f,0.f,0.f,0.f};
    accK[s] = (f32x4){0.f,0.f,0.f,0.f};
    accV[s] = (f32x4){0.f,0.f,0.f,0.f};
  }
  const float* xrow = X + (size_t)(R*32 + rh*16 + l15)*E_ + 8*g;

  // prologue: stage (t0,Q) into buf0 (2 chunks of 16KB); X(0)
  #pragma unroll
  for (int r = 0; r < 2; ++r)
    gload_lds16(WpQ + r*8192 + w*512 + l*8, &Wt[0][r*8192 + w*512]);
  float4 c0 = *(const float4*)xrow;
  float4 c1 = *(const float4*)(xrow + 4);
  asm volatile("s_waitcnt vmcnt(0)" ::: "memory");
  __syncthreads();

  float xsq = 0.f;

  #pragma unroll 1
  for (int t = 0; t < 16; ++t) {
    int p0 = t & 1;
    short8 ahi, alo;
    // ---- Q vstep: compute Wt[p0], stage K(t) -> Wt[p0^1]
    {
      float av[8] = {c0.x,c0.y,c0.z,c0.w,c1.x,c1.y,c1.z,c1.w};
      #pragma unroll
      for (int j = 0; j < 8; ++j) {
        unsigned hb = f2bf(av[j]);
        ahi[j] = (short)hb;
        alo[j] = (short)f2bf(av[j] - bf2f(hb));
        xsq = fmaf(av[j], av[j], xsq);
      }
      const unsigned short* src = WpK + (size_t)t*16384 + w*512 + l*8;
      #pragma unroll
      for (int r = 0; r < 2; ++r)
        gload_lds16(src + r*8192, &Wt[p0^1][r*8192 + w*512]);
      __builtin_amdgcn_sched_barrier(0);
      const unsigned short* wb = &Wt[p0][(4*ng)*512] + l*8;
      #pragma unroll
      for (int s = 0; s < 4; ++s) {
        short8 bhi = *(const short8*)(wb + s*512);
        accQ[s] = __builtin_amdgcn_mfma_f32_16x16x32_bf16(ahi, bhi, accQ[s], 0, 0, 0);
        accQ[s] = __builtin_amdgcn_mfma_f32_16x16x32_bf16(alo, bhi, accQ[s], 0, 0, 0);
      }
      asm volatile("s_waitcnt vmcnt(0)" ::: "memory");
      __builtin_amdgcn_s_barrier();
    }
    // ---- K vstep: compute Wt[p0^1], stage V(t) -> Wt[p0]; X(t+1) prefetch
    {
      const unsigned short* src = WpV + (size_t)t*16384 + w*512 + l*8;
      #pragma unroll
      for (int r = 0; r < 2; ++r)
        gload_lds16(src + r*8192, &Wt[p0][r*8192 + w*512]);
      __builtin_amdgcn_sched_barrier(0);
      if (t < 15) {
        c0 = *(const float4*)(xrow + 32*(t+1));
        c1 = *(const float4*)(xrow + 32*(t+1) + 4);
      }
      const unsigned short* wb = &Wt[p0^1][(4*ng)*512] + l*8;
      #pragma unroll
      for (int s = 0; s < 4; ++s) {
        short8 bhi = *(const short8*)(wb + s*512);
        accK[s] = __builtin_amdgcn_mfma_f32_16x16x32_bf16(ahi, bhi, accK[s], 0, 0, 0);
        accK[s] = __builtin_amdgcn_mfma_f32_16x16x32_bf16(alo, bhi, accK[s], 0, 0, 0);
      }
      // drain V-stage (oldest 2); X loads (2 newest) stay in flight
      if (t < 15) { asm volatile("s_waitcnt vmcnt(2)" ::: "memory"); }
      else        { asm volatile("s_waitcnt vmcnt(0)" ::: "memory"); }
      __builtin_amdgcn_s_barrier();
    }
    // ---- V vstep: compute Wt[p0], stage Q(t+1) -> Wt[p0^1]
    {
      if (t < 15) {
        const unsigned short* src = WpQ + (size_t)(t+1)*16384 + w*512 + l*8;
        #pragma unroll
        for (int r = 0; r < 2; ++r)
          gload_lds16(src + r*8192, &Wt[p0^1][r*8192 + w*512]);
      }
      __builtin_amdgcn_sched_barrier(0);
      const unsigned short* wb = &Wt[p0][(4*ng)*512] + l*8;
      #pragma unroll
      for (int s = 0; s < 4; ++s) {
        short8 bhi = *(const short8*)(wb + s*512);
        accV[s] = __builtin_amdgcn_mfma_f32_16x16x32_bf16(ahi, bhi, accV[s], 0, 0, 0);
        accV[s] = __builtin_amdgcn_mfma_f32_16x16x32_bf16(alo, bhi, accV[s], 0, 0, 0);
      }
      asm volatile("s_waitcnt vmcnt(0)" ::: "memory");
      __builtin_amdgcn_s_barrier();
    }
  }

  // ---- inline row-stats
  xsq += __shfl_xor(xsq, 16, 64);
  xsq += __shfl_xor(xsq, 32, 64);
  float xnv4[4], art4[4];
  #pragma unroll
  for (int i = 0; i < 4; ++i) {
    float s2 = __shfl(xsq, 4*g + i, 64);
    float xnv = fmaxf(sqrtf(s2), 1e-15f);
    float aa = fminf(xnv, 1.f - 1e-7f);
    xnv4[i] = xnv;
    art4[i] = 0.5f * (log1pf(aa) - log1pf(-aa));
  }

  // ---- per-matrix Mobius epilogue + packed store
  auto epi = [&](const f32x4* acc, const float* bvec, int mode,
                 unsigned short* outHi, float* normOut) {
    float bl[4];
    #pragma unroll
    for (int s = 0; s < 4; ++s) bl[s] = bvec[16*(4*ng+s) + l15];
    float m2p[4] = {0.f,0.f,0.f,0.f}, mbp[4] = {0.f,0.f,0.f,0.f}, b2p = 0.f;
    #pragma unroll
    for (int s = 0; s < 4; ++s) {
      b2p += bl[s]*bl[s];
      #pragma unroll
      for (int i = 0; i < 4; ++i) {
        m2p[i] = fmaf(acc[s][i], acc[s][i], m2p[i]);
        mbp[i] = fmaf(acc[s][i], bl[s], mbp[i]);
      }
    }
    #pragma unroll
    for (int off = 1; off <= 8; off <<= 1) {
      b2p += __shfl_xor(b2p, off, 64);
      #pragma unroll
      for (int i = 0; i < 4; ++i) {
        m2p[i] += __shfl_xor(m2p[i], off, 64);
        mbp[i] += __shfl_xor(mbp[i], off, 64);
      }
    }
    __syncthreads();
    if (l == 0) smb2[w] = b2p;
    if (l15 == 0) {
      #pragma unroll
      for (int i = 0; i < 4; ++i) { smM[ng][rh][g][i] = m2p[i]; smB[ng][rh][g][i] = mbp[i]; }
    }
    __syncthreads();
    float b2 = 0.f;
    #pragma unroll
    for (int q = 0; q < 8; ++q) b2 += smb2[2*q];
    float G[4], Hc[4];
    #pragma unroll
    for (int i = 0; i < 4; ++i) {
      float m2 = 0.f, mb = 0.f;
      #pragma unroll
      for (int q = 0; q < 8; ++q) { m2 += smM[q][rh][g][i]; mb += smB[q][rh][g][i]; }
      float xn = xnv4[i], art = art4[i];
      float mn = fmaxf(sqrtf(m2), 1e-15f);
      float t = tanhf(mn / xn * art);
      float alpha, rn;
      if (m2 > 0.f) { alpha = t / mn; rn = t; } else { alpha = 0.f; rn = 0.f; }
      if (rn > MAXN) { alpha *= MAXN / rn; rn = MAXN; }        // project(res)
      float x2r = rn * rn;
      float xy = alpha * mb;
      float A  = 1.f + 2.f*xy + b2;
      float Bc = 1.f - x2r;
      float den = fmaxf(1.f + 2.f*xy + x2r*b2, 1e-15f);
      float n2v = (A*A*x2r + 2.f*A*Bc*xy + Bc*Bc*b2) / (den*den);
      float nn = fmaxf(sqrtf(n2v), 1e-15f);
      float sc = (nn > MAXN) ? (MAXN / nn) : 1.f;              // project(add)
      G[i]  = sc * A * alpha / den;
      Hc[i] = sc * Bc / den;
    }
    #pragma unroll
    for (int i = 0; i < 4; ++i) {
      int grow = R*32 + rh*16 + 4*g + i;
      int bb = grow >> 11, seq = grow & 2047;
      int tile = seq >> 6;
      float hn = 0.f;
      #pragma unroll
      for (int s = 0; s < 4; ++s) {
        int col = 16*(4*ng+s) + l15;
        float v = G[i]*acc[s][i] + Hc[i]*bl[s];
        int h = col >> 6, c = col & 63;
        size_t base;
        if (mode == 2) {   // V layout
          int kt = (seq >> 5) & 1, gp = (seq >> 3) & 3, jv = seq & 7;
          int dn = c >> 4, lt = (c & 15) | (gp << 4);
          base = ((size_t)((bb*8 + h)*32 + tile))*4096 + (size_t)((kt*4+dn)*64 + lt)*8 + jv;
        } else {           // Q/K layout
          int nf = (seq >> 4) & 3, lt15 = seq & 15;
          int dt = c >> 5, m = (c >> 3) & 3, j = c & 7;
          base = ((size_t)((bb*8 + h)*32 + tile))*4096 + (size_t)((dt*4+nf)*64 + (lt15|(m<<4)))*8 + j;
        }
        outHi[base] = (unsigned short)f2bf(v);
        if (mode == 1) hn += v*v;
      }
      if (mode == 1) {
        hn += __shfl_xor(hn,1,64); hn += __shfl_xor(hn,2,64);
        hn += __shfl_xor(hn,4,64); hn += __shfl_xor(hn,8,64);
        if (l15 == 0)
          normOut[((size_t)(bb*8 + ng))*S_ + seq] = fminf(hn, 1.f - 1e-5f);
      }
    }
  };
  epi(accQ, bq_, 1, Qhi, qn);
  epi(accK, bk_, 1, Khi, kn);
  epi(accV, bv_, 2, Vhi, nullptr);
}

// ---- fused O-linear: W hi-only, double-buffered 32KB slices, X depth-2 prefetch.
__global__ __launch_bounds__(1024, 4) void fused_o(const float* __restrict__ X,
    const unsigned short* __restrict__ Wp, const float* __restrict__ bvec,
    float* __restrict__ outF) {
  __shared__ __align__(16) unsigned short Wt[2][16384];
  __shared__ float smM[8][2][4][4], smB[8][2][4][4], smb2[16];
  int tid = threadIdx.x;
  int w = tid >> 6, l = tid & 63;
  int l15 = l & 15, g = l >> 4;
  int rh = w & 1, ng = w >> 1;
  int R = blockIdx.x;

  f32x4 acc[4];
  #pragma unroll
  for (int s = 0; s < 4; ++s) acc[s] = (f32x4){0.f,0.f,0.f,0.f};
  const float* xrow = X + (size_t)(R*32 + rh*16 + l15)*E_ + 8*g;

  #pragma unroll
  for (int r = 0; r < 2; ++r)
    gload_lds16(Wp + r*8192 + w*512 + l*8, &Wt[0][r*8192 + w*512]);
  float4 xa0 = *(const float4*)(xrow);
  float4 xa1 = *(const float4*)(xrow + 4);
  float4 xb0 = *(const float4*)(xrow + 32);
  float4 xb1 = *(const float4*)(xrow + 36);
  asm volatile("s_waitcnt vmcnt(0)" ::: "memory");
  __syncthreads();

  float xsq = 0.f;
  auto step = [&](int t, float4& c0, float4& c1) {
    int cur = t & 1;
    if (t < 15) {
      const unsigned short* src = Wp + (size_t)(t+1)*16384 + w*512 + l*8;
      #pragma unroll
      for (int r = 0; r < 2; ++r)
        gload_lds16(src + r*8192, &Wt[cur^1][r*8192 + w*512]);
    }
    __builtin_amdgcn_sched_barrier(0);
    float av[8] = {c0.x,c0.y,c0.z,c0.w,c1.x,c1.y,c1.z,c1.w};
    short8 ahi, alo;
    #pragma unroll
    for (int j = 0; j < 8; ++j) {
      unsigned hb = f2bf(av[j]);
      ahi[j] = (short)hb;
      alo[j] = (short)f2bf(av[j] - bf2f(hb));
      xsq = fmaf(av[j], av[j], xsq);
    }
    if (t < 14) {
      c0 = *(const float4*)(xrow + 32*(t+2));
      c1 = *(const float4*)(xrow + 32*(t+2) + 4);
    }
    const unsigned short* wb = &Wt[cur][(4*ng)*512] + l*8;
    #pragma unroll
    for (int s = 0; s < 4; ++s) {
      short8 bhi = *(const short8*)(wb + s*512);
      acc[s] = __builtin_amdgcn_mfma_f32_16x16x32_bf16(ahi, bhi, acc[s], 0, 0, 0);
      acc[s] = __builtin_amdgcn_mfma_f32_16x16x32_bf16(alo, bhi, acc[s], 0, 0, 0);
    }
    if (t < 14) { asm volatile("s_waitcnt vmcnt(2)" ::: "memory"); }
    else        { asm volatile("s_waitcnt vmcnt(0)" ::: "memory"); }
    __builtin_amdgcn_s_barrier();
  };
  #pragma unroll 1
  for (int tt = 0; tt < 16; tt += 2) {
    step(tt,   xa0, xa1);
    step(tt+1, xb0, xb1);
  }

  xsq += __shfl_xor(xsq, 16, 64);
  xsq += __shfl_xor(xsq, 32, 64);
  float xnv4[4], art4[4];
  #pragma unroll
  for (int i = 0; i < 4; ++i) {
    float s2 = __shfl(xsq, 4*g + i, 64);
    float xnv = fmaxf(sqrtf(s2), 1e-15f);
    float aa = fminf(xnv, 1.f - 1e-7f);
    xnv4[i] = xnv;
    art4[i] = 0.5f * (log1pf(aa) - log1pf(-aa));
  }

  float bl[4];
  #pragma unroll
  for (int s = 0; s < 4; ++s) bl[s] = bvec[16*(4*ng+s) + l15];
  float m2p[4] = {0.f,0.f,0.f,0.f}, mbp[4] = {0.f,0.f,0.f,0.f}, b2p = 0.f;
  #pragma unroll
  for (int s = 0; s < 4; ++s) {
    b2p += bl[s]*bl[s];
    #pragma unroll
    for (int i = 0; i < 4; ++i) {
      m2p[i] = fmaf(acc[s][i], acc[s][i], m2p[i]);
      mbp[i] = fmaf(acc[s][i], bl[s], mbp[i]);
    }
  }
  #pragma unroll
  for (int off = 1; off <= 8; off <<= 1) {
    b2p += __shfl_xor(b2p, off, 64);
    #pragma unroll
    for (int i = 0; i < 4; ++i) {
      m2p[i] += __shfl_xor(m2p[i], off, 64);
      mbp[i] += __shfl_xor(mbp[i], off, 64);
    }
  }
  __syncthreads();
  if (l == 0) smb2[w] = b2p;
  if (l15 == 0) {
    #pragma unroll
    for (int i = 0; i < 4; ++i) { smM[ng][rh][g][i] = m2p[i]; smB[ng][rh][g][i] = mbp[i]; }
  }
  __syncthreads();
  float b2 = 0.f;
  #pragma unroll
  for (int q = 0; q < 8; ++q) b2 += smb2[2*q];
  #pragma unroll
  for (int i = 0; i < 4; ++i) {
    float m2 = 0.f, mb = 0.f;
    #pragma unroll
    for (int q = 0; q < 8; ++q) { m2 += smM[q][rh][g][i]; mb += smB[q][rh][g][i]; }
    float xn = xnv4[i], art = art4[i];
    float mn = fmaxf(sqrtf(m2), 1e-15f);
    float t = tanhf(mn / xn * art);
    float alpha, rn;
    if (m2 > 0.f) { alpha = t / mn; rn = t; } else { alpha = 0.f; rn = 0.f; }
    if (rn > MAXN) { alpha *= MAXN / rn; rn = MAXN; }
    float x2r = rn * rn;
    float xy = alpha * mb;
    float A  = 1.f + 2.f*xy + b2;
    float Bc = 1.f - x2r;
    float den = fmaxf(1.f + 2.f*xy + x2r*b2, 1e-15f);
    float n2v = (A*A*x2r + 2.f*A*Bc*xy + Bc*Bc*b2) / (den*den);
    float nn = fmaxf(sqrtf(n2v), 1e-15f);
    float sc = (nn > MAXN) ? (MAXN / nn) : 1.f;
    float G = sc * A * alpha / den;
    float Hc = sc * Bc / den;
    int grow = R*32 + rh*16 + 4*g + i;
    #pragma unroll
    for (int s = 0; s < 4; ++s)
      outF[(size_t)grow*E_ + 16*(4*ng+s) + l15] = G*acc[s][i] + Hc*bl[s];
  }
}

// ---- Attention v9: 32KB LDS (single-buffer K staged after barrier-A, V dbuf),
// rcp-factored softmax (den = qd*kd, error 1e-5 rel). 4 blocks/CU.
__global__ __launch_bounds__(256, 4) void attn_kernel(
    const unsigned short* __restrict__ Qhi, const unsigned short* __restrict__ Khi,
    const unsigned short* __restrict__ Vhi,
    const float* __restrict__ qn_arr, const float* __restrict__ kn_arr,
    float* __restrict__ Out) {
  __shared__ __align__(16) unsigned short Kf[4096];       // 8KB, single buffer
  __shared__ __align__(16) unsigned short Vf[2][4096];    // 16KB
  __shared__ __align__(16) unsigned short Pf[4][1024];    // 8KB -> total 32KB

  int tid = threadIdx.x;
  int w = tid >> 6, l = tid & 63;
  int l15 = l & 15, g = l >> 4;

  int bid = blockIdx.x;                 // XCD swizzle: xcd owns bh 4*xcd..4*xcd+3
  int xcd = bid & 7, idx = bid >> 3;
  int bh = xcd * 4 + (idx >> 5);
  int qblk = idx & 31;
  int b = bh >> 3, h = bh & 7;
  int qb = qblk * 64;

  const unsigned short* qbase = Qhi + ((size_t)(bh*32 + qblk))*4096;
  short8 qhi[2];
  #pragma unroll
  for (int dt = 0; dt < 2; ++dt)
    qhi[dt] = *(const short8*)(qbase + (size_t)((dt*4 + w)*64 + l)*8);
  float qnv[4], qd[4], rq[4];
  #pragma unroll
  for (int i = 0; i < 4; ++i) {
    qnv[i] = qn_arr[(size_t)bh*S_ + qb + 16*w + 4*g + i];
    qd[i] = 1.f - qnv[i];
    rq[i] = __builtin_amdgcn_rcpf(qd[i]);
  }

  f32x4 Oacc[4];
  #pragma unroll
  for (int dn = 0; dn < 4; ++dn) Oacc[dn] = (f32x4){0.f,0.f,0.f,0.f};
  float lp[4] = {0.f,0.f,0.f,0.f};

  const unsigned short* Kbh = Khi + ((size_t)bh*32)*4096;
  const unsigned short* Vbh = Vhi + ((size_t)bh*32)*4096;
  const float* knp = kn_arr + (size_t)bh*S_;

  // prologue: K(0) -> Kf, V(0) -> Vf[0]
  #pragma unroll
  for (int r = 0; r < 2; ++r) {
    gload_lds16(Kbh + r*2048 + w*512 + l*8, &Kf[r*2048 + w*512]);
    gload_lds16(Vbh + r*2048 + w*512 + l*8, &Vf[0][r*2048 + w*512]);
  }
  asm volatile("s_waitcnt vmcnt(0)" ::: "memory");
  __syncthreads();

  #pragma unroll 1
  for (int tile = 0; tile < 32; ++tile) {
    int cur = tile & 1;
    int kb = tile * 64;
    float knc[4];
    #pragma unroll
    for (int n = 0; n < 4; ++n) knc[n] = knp[kb + 16*n + l15];
    // ---- QK^T + softmax + P store (reads Kf)
    #pragma unroll
    for (int n = 0; n < 4; ++n) {
      f32x4 Cn = (f32x4){0.f,0.f,0.f,0.f};
      #pragma unroll
      for (int dt = 0; dt < 2; ++dt) {
        short8 kfr = *(const short8*)&Kf[((dt*4 + n)*64 + l)*8];
        Cn = __builtin_amdgcn_mfma_f32_16x16x32_bf16(qhi[dt], kfr, Cn, 0, 0, 0);
      }
      float kd = 1.f - knc[n];
      float rkn = __builtin_amdgcn_rcpf(kd);
      int cbase = (n >> 1)*64 + 16*((2*n + (l15 >> 3)) & 3) + 4*g;
      int csb = cbase ^ ((cbase >> 3) & 7);      // cs_i = csb ^ i
      int j7 = l15 & 7;
      #pragma unroll
      for (int i = 0; i < 4; ++i) {
        float num = fmaf(-qnv[i], knc[n], Cn[i]);
        float d2 = fmaxf(num * (rq[i]*rkn), 5e-6f);
        float sq = d2 * __builtin_amdgcn_rsqf(d2);             // sqrt(d2)
        float p = __builtin_amdgcn_exp2f(-0.25503386f * sq);   // exp(-sqrt(2*d2)/8)
        unsigned u = __float_as_uint(p);
        lp[i] += __uint_as_float(u & 0xffff0000u);             // == stored bf16 value
        Pf[w][((csb ^ i) << 3) + j7] = (unsigned short)(u >> 16);
      }
    }
    __builtin_amdgcn_s_barrier();       // barrier A: all QK reads of Kf done
    if (tile < 31) {                    // stage K(t+1) -> Kf (older), V(t+1) -> Vf[cur^1]
      const unsigned short* kp = Kbh + ((size_t)(tile+1))*4096;
      const unsigned short* vp = Vbh + ((size_t)(tile+1))*4096;
      #pragma unroll
      for (int r = 0; r < 2; ++r)
        gload_lds16(kp + r*2048 + w*512 + l*8, &Kf[r*2048 + w*512]);
      #pragma unroll
      for (int r = 0; r < 2; ++r)
        gload_lds16(vp + r*2048 + w*512 + l*8, &Vf[cur^1][r*2048 + w*512]);
    }
    __builtin_amdgcn_sched_barrier(0);  // stages issue before PV's ds reads
    // ---- PV (Vf[cur] = V(tile): drained by this tile's knc wait)
    short8 pa0, pa1;
    { int c = l;       int cs = c ^ ((c >> 3) & 7); pa0 = *(const short8*)&Pf[w][cs*8]; }
    { int c = 64 + l;  int cs = c ^ ((c >> 3) & 7); pa1 = *(const short8*)&Pf[w][cs*8]; }
    #pragma unroll
    for (int dn = 0; dn < 4; ++dn) {
      short8 v0 = *(const short8*)&Vf[cur][((0*4 + dn)*64 + l)*8];
      short8 v1 = *(const short8*)&Vf[cur][((1*4 + dn)*64 + l)*8];
      f32x4 o = Oacc[dn];
      o = __builtin_amdgcn_mfma_f32_16x16x32_bf16(pa0, v0, o, 0, 0, 0);
      o = __builtin_amdgcn_mfma_f32_16x16x32_bf16(pa1, v1, o, 0, 0, 0);
      Oacc[dn] = o;
    }
    asm volatile("s_waitcnt vmcnt(2)" ::: "memory");  // drain K-stage, leave V-stage
    __builtin_amdgcn_s_barrier();
  }

  #pragma unroll
  for (int i = 0; i < 4; ++i) {
    lp[i] += __shfl_xor(lp[i], 1, 64);
    lp[i] += __shfl_xor(lp[i], 2, 64);
    lp[i] += __shfl_xor(lp[i], 4, 64);
    lp[i] += __shfl_xor(lp[i], 8, 64);
    lp[i] = 1.f / lp[i];
  }
  #pragma unroll
  for (int i = 0; i < 4; ++i) {
    size_t orow = (size_t)(b*S_ + qb + 16*w + 4*g + i)*E_ + h*Dh_;
    #pragma unroll
    for (int dn = 0; dn < 4; ++dn)
      Out[orow + 16*dn + l15] = Oacc[dn][i] * lp[i];
  }
}

extern "C" void kernel_launch(void* const* d_in, const int* in_sizes, int n_in,
                              void* d_out, int out_size, void* d_ws, size_t ws_size,
                              hipStream_t stream) {
  const float* x  = (const float*)d_in[0];
  const float* Wq = (const float*)d_in[1];
  const float* bq = (const float*)d_in[2];
  const float* Wk = (const float*)d_in[3];
  const float* bk = (const float*)d_in[4];
  const float* Wv = (const float*)d_in[5];
  const float* bv = (const float*)d_in[6];
  const float* Wo = (const float*)d_in[7];
  const float* bo = (const float*)d_in[8];
  float* out = (float*)d_out;

  char* p = (char*)d_ws;
  unsigned short* Wp  = (unsigned short*)p; p += (size_t)2  << 20;  // 2 MB (hi only)
  unsigned short* Qhi = (unsigned short*)p; p += (size_t)8  << 20;
  unsigned short* Khi = (unsigned short*)p; p += (size_t)8  << 20;
  unsigned short* Vhi = (unsigned short*)p; p += (size_t)8  << 20;
  float* ao   = (float*)p; p += (size_t)16 << 20;                   // attn out fp32
  float* qn   = (float*)p; p += (size_t)B_*H_*S_ * 4;
  float* kn   = (float*)p; p += (size_t)B_*H_*S_ * 4;
  // total ~= 42.5 MB

  pack_w_kernel<<<dim3(32, 4), dim3(256), 0, stream>>>(Wq, Wk, Wv, Wo, Wp);
  fused_qkv<<<dim3(BS_/32), dim3(1024), 0, stream>>>(x, Wp, bq, bk, bv, Qhi, Khi, Vhi, qn, kn);
  attn_kernel<<<dim3(1024), dim3(256), 0, stream>>>(Qhi, Khi, Vhi, qn, kn, ao);
  fused_o<<<dim3(BS_/32), dim3(1024), 0, stream>>>(ao, Wp + 3*262144, bo, out);
}

// Round 13
// 167.760 us; speedup vs baseline: 1.6690x; 1.1887x over previous
//
#include <hip/hip_runtime.h>
#include <math.h>

#define B_ 4
#define S_ 2048
#define E_ 512
#define H_ 8
#define Dh_ 64
#define BS_ (B_*S_)
#define MAXN 0.996f   // (1 - 4e-3)/sqrt(c), c=1

typedef __attribute__((ext_vector_type(8))) short short8;
typedef __attribute__((ext_vector_type(4))) float f32x4;

__device__ __forceinline__ unsigned f2bf(float x) {            // RNE f32->bf16 bits
  unsigned u = __float_as_uint(x);
  return (u + 0x7fffu + ((u >> 16) & 1u)) >> 16;
}
__device__ __forceinline__ float bf2f(unsigned b) {
  return __uint_as_float(b << 16);
}

__device__ __forceinline__ void gload_lds16(const void* g, void* lds) {
  __builtin_amdgcn_global_load_lds(
      (const __attribute__((address_space(1))) unsigned int*)g,
      (__attribute__((address_space(3))) unsigned int*)lds, 16, 0, 0);
}

// ---- pack W matrices: t-major B-frag order, HI ONLY
// Wp[mat][ (t*32 + n)*512 + l*8 + j ];  element: W[16n + (l&15)][32t + 8*(l>>4) + j]
__global__ __launch_bounds__(256) void pack_w_kernel(const float* __restrict__ W0,
    const float* __restrict__ W1, const float* __restrict__ W2,
    const float* __restrict__ W3, unsigned short* __restrict__ Wp) {
  const float* W = (blockIdx.y == 0) ? W0 : (blockIdx.y == 1) ? W1
                 : (blockIdx.y == 2) ? W2 : W3;
  unsigned short* dst = Wp + (size_t)blockIdx.y * 262144;
  int l = threadIdx.x & 63, tq = threadIdx.x >> 6;
  int n = blockIdx.x;
  int col = 16*n + (l & 15);
  int k0 = 8 * (l >> 4);
  #pragma unroll
  for (int tt = 0; tt < 4; ++tt) {
    int t = tq*4 + tt;
    const float* wp_ = W + (size_t)col * E_ + 32*t + k0;
    float4 a0 = *(const float4*)wp_, a1 = *(const float4*)(wp_ + 4);
    float av[8] = {a0.x,a0.y,a0.z,a0.w,a1.x,a1.y,a1.z,a1.w};
    short8 hi;
    #pragma unroll
    for (int j = 0; j < 8; ++j) hi[j] = (short)f2bf(av[j]);
    *(short8*)(dst + ((size_t)(t*32 + n))*512 + l*8) = hi;
  }
}

// ---- QKV linears: barrier-free main loop, W B-frags read DIRECTLY from L2.
// Block = 4 waves x (16 rows, 8 n-tiles) = 16 rows x 512 cols, one matrix
// (blockIdx.y). Grid 512x3 = 1536 blocks -> ~20 waves/CU. Inline row-stats.
__global__ __launch_bounds__(256, 4) void qkv_linear(const float* __restrict__ X,
    const unsigned short* __restrict__ Wp,
    const float* __restrict__ bq_, const float* __restrict__ bk_,
    const float* __restrict__ bv_,
    unsigned short* __restrict__ Qhi, unsigned short* __restrict__ Khi,
    unsigned short* __restrict__ Vhi,
    float* __restrict__ qn, float* __restrict__ kn) {
  __shared__ float smM[4][4][4], smB[4][4][4], smb2[4];
  int tid = threadIdx.x;
  int w = tid >> 6, l = tid & 63;
  int l15 = l & 15, g = l >> 4;
  int R = blockIdx.x;                       // rows 16R .. 16R+15
  int mat = blockIdx.y;
  const unsigned short* Wm = Wp + (size_t)mat * 262144;
  const float* bvec = (mat == 0) ? bq_ : (mat == 1) ? bk_ : bv_;
  unsigned short* outHi = (mat == 0) ? Qhi : (mat == 1) ? Khi : Vhi;
  float* normOut = (mat == 0) ? qn : kn;

  f32x4 acc[8];
  #pragma unroll
  for (int s = 0; s < 8; ++s) acc[s] = (f32x4){0.f,0.f,0.f,0.f};
  const float* xrow = X + (size_t)(R*16 + l15)*E_ + 8*g;

  float4 c0 = *(const float4*)xrow;
  float4 c1 = *(const float4*)(xrow + 4);
  float xsq = 0.f;

  #pragma unroll 2
  for (int t = 0; t < 16; ++t) {
    float av[8] = {c0.x,c0.y,c0.z,c0.w,c1.x,c1.y,c1.z,c1.w};
    short8 ahi, alo;
    #pragma unroll
    for (int j = 0; j < 8; ++j) {
      unsigned hb = f2bf(av[j]);
      ahi[j] = (short)hb;
      alo[j] = (short)f2bf(av[j] - bf2f(hb));
      xsq = fmaf(av[j], av[j], xsq);
    }
    if (t < 15) {                            // X(t+1) prefetch
      c0 = *(const float4*)(xrow + 32*(t+1));
      c1 = *(const float4*)(xrow + 32*(t+1) + 4);
    }
    const unsigned short* wb = Wm + ((size_t)(t*32 + 8*w))*512 + (size_t)l*8;
    #pragma unroll
    for (int s = 0; s < 8; ++s) {
      short8 bhi = *(const short8*)(wb + s*512);
      acc[s] = __builtin_amdgcn_mfma_f32_16x16x32_bf16(ahi, bhi, acc[s], 0, 0, 0);
      acc[s] = __builtin_amdgcn_mfma_f32_16x16x32_bf16(alo, bhi, acc[s], 0, 0, 0);
    }
  }

  // ---- inline row-stats (xsq identical in all 4 waves; reduce over g)
  xsq += __shfl_xor(xsq, 16, 64);
  xsq += __shfl_xor(xsq, 32, 64);
  float xnv4[4], art4[4];
  #pragma unroll
  for (int i = 0; i < 4; ++i) {
    float s2 = __shfl(xsq, 4*g + i, 64);
    float xnv = fmaxf(sqrtf(s2), 1e-15f);
    float aa = fminf(xnv, 1.f - 1e-7f);
    xnv4[i] = xnv;
    art4[i] = 0.5f * (log1pf(aa) - log1pf(-aa));
  }

  // ---- epilogue: partials over this wave's 8 n-tiles, cross-wave LDS combine
  float bl[8];
  #pragma unroll
  for (int s = 0; s < 8; ++s) bl[s] = bvec[16*(8*w+s) + l15];
  float m2p[4] = {0.f,0.f,0.f,0.f}, mbp[4] = {0.f,0.f,0.f,0.f}, b2p = 0.f;
  #pragma unroll
  for (int s = 0; s < 8; ++s) {
    b2p += bl[s]*bl[s];
    #pragma unroll
    for (int i = 0; i < 4; ++i) {
      m2p[i] = fmaf(acc[s][i], acc[s][i], m2p[i]);
      mbp[i] = fmaf(acc[s][i], bl[s], mbp[i]);
    }
  }
  #pragma unroll
  for (int off = 1; off <= 8; off <<= 1) {
    b2p += __shfl_xor(b2p, off, 64);
    #pragma unroll
    for (int i = 0; i < 4; ++i) {
      m2p[i] += __shfl_xor(m2p[i], off, 64);
      mbp[i] += __shfl_xor(mbp[i], off, 64);
    }
  }
  if (l == 0) smb2[w] = b2p;
  if (l15 == 0) {
    #pragma unroll
    for (int i = 0; i < 4; ++i) { smM[w][g][i] = m2p[i]; smB[w][g][i] = mbp[i]; }
  }
  __syncthreads();
  float b2 = smb2[0] + smb2[1] + smb2[2] + smb2[3];
  float G[4], Hc[4];
  #pragma unroll
  for (int i = 0; i < 4; ++i) {
    float m2 = smM[0][g][i]+smM[1][g][i]+smM[2][g][i]+smM[3][g][i];
    float mb = smB[0][g][i]+smB[1][g][i]+smB[2][g][i]+smB[3][g][i];
    float xn = xnv4[i], art = art4[i];
    float mn = fmaxf(sqrtf(m2), 1e-15f);
    float t = tanhf(mn / xn * art);
    float alpha, rn;
    if (m2 > 0.f) { alpha = t / mn; rn = t; } else { alpha = 0.f; rn = 0.f; }
    if (rn > MAXN) { alpha *= MAXN / rn; rn = MAXN; }          // project(res)
    float x2r = rn * rn;
    float xy = alpha * mb;
    float A  = 1.f + 2.f*xy + b2;
    float Bc = 1.f - x2r;
    float den = fmaxf(1.f + 2.f*xy + x2r*b2, 1e-15f);
    float n2v = (A*A*x2r + 2.f*A*Bc*xy + Bc*Bc*b2) / (den*den);
    float nn = fmaxf(sqrtf(n2v), 1e-15f);
    float sc = (nn > MAXN) ? (MAXN / nn) : 1.f;                // project(add)
    G[i]  = sc * A * alpha / den;
    Hc[i] = sc * Bc / den;
  }

  // ---- packed store + head norms (wave w covers heads 2w, 2w+1)
  #pragma unroll
  for (int i = 0; i < 4; ++i) {
    int grow = R*16 + 4*g + i;
    int bb = grow >> 11, seq = grow & 2047;
    int tile = seq >> 6;
    float hn0 = 0.f, hn1 = 0.f;
    #pragma unroll
    for (int s = 0; s < 8; ++s) {
      int col = 16*(8*w+s) + l15;
      float v = G[i]*acc[s][i] + Hc[i]*bl[s];
      int h = col >> 6, c = col & 63;
      size_t base;
      if (mat == 2) {    // V layout
        int kt = (seq >> 5) & 1, gp = (seq >> 3) & 3, jv = seq & 7;
        int dn = c >> 4, lt = (c & 15) | (gp << 4);
        base = ((size_t)((bb*8 + h)*32 + tile))*4096 + (size_t)((kt*4+dn)*64 + lt)*8 + jv;
      } else {           // Q/K layout
        int nf = (seq >> 4) & 3, lt15 = seq & 15;
        int dt = c >> 5, m = (c >> 3) & 3, j = c & 7;
        base = ((size_t)((bb*8 + h)*32 + tile))*4096 + (size_t)((dt*4+nf)*64 + (lt15|(m<<4)))*8 + j;
      }
      outHi[base] = (unsigned short)f2bf(v);
      if (mat < 2) { if (s < 4) hn0 += v*v; else hn1 += v*v; }
    }
    if (mat < 2) {
      hn0 += __shfl_xor(hn0,1,64); hn0 += __shfl_xor(hn0,2,64);
      hn0 += __shfl_xor(hn0,4,64); hn0 += __shfl_xor(hn0,8,64);
      hn1 += __shfl_xor(hn1,1,64); hn1 += __shfl_xor(hn1,2,64);
      hn1 += __shfl_xor(hn1,4,64); hn1 += __shfl_xor(hn1,8,64);
      if (l15 == 0) {
        normOut[((size_t)(bb*8 + 2*w + 0))*S_ + seq] = fminf(hn0, 1.f - 1e-5f);
        normOut[((size_t)(bb*8 + 2*w + 1))*S_ + seq] = fminf(hn1, 1.f - 1e-5f);
      }
    }
  }
}

// ---- O-linear: same barrier-free direct-L2 structure, fp32 row output.
__global__ __launch_bounds__(256, 4) void o_linear(const float* __restrict__ X,
    const unsigned short* __restrict__ Wp, const float* __restrict__ bvec,
    float* __restrict__ outF) {
  __shared__ float smM[4][4][4], smB[4][4][4], smb2[4];
  int tid = threadIdx.x;
  int w = tid >> 6, l = tid & 63;
  int l15 = l & 15, g = l >> 4;
  int R = blockIdx.x;

  f32x4 acc[8];
  #pragma unroll
  for (int s = 0; s < 8; ++s) acc[s] = (f32x4){0.f,0.f,0.f,0.f};
  const float* xrow = X + (size_t)(R*16 + l15)*E_ + 8*g;

  float4 c0 = *(const float4*)xrow;
  float4 c1 = *(const float4*)(xrow + 4);
  float xsq = 0.f;

  #pragma unroll 2
  for (int t = 0; t < 16; ++t) {
    float av[8] = {c0.x,c0.y,c0.z,c0.w,c1.x,c1.y,c1.z,c1.w};
    short8 ahi, alo;
    #pragma unroll
    for (int j = 0; j < 8; ++j) {
      unsigned hb = f2bf(av[j]);
      ahi[j] = (short)hb;
      alo[j] = (short)f2bf(av[j] - bf2f(hb));
      xsq = fmaf(av[j], av[j], xsq);
    }
    if (t < 15) {
      c0 = *(const float4*)(xrow + 32*(t+1));
      c1 = *(const float4*)(xrow + 32*(t+1) + 4);
    }
    const unsigned short* wb = Wp + ((size_t)(t*32 + 8*w))*512 + (size_t)l*8;
    #pragma unroll
    for (int s = 0; s < 8; ++s) {
      short8 bhi = *(const short8*)(wb + s*512);
      acc[s] = __builtin_amdgcn_mfma_f32_16x16x32_bf16(ahi, bhi, acc[s], 0, 0, 0);
      acc[s] = __builtin_amdgcn_mfma_f32_16x16x32_bf16(alo, bhi, acc[s], 0, 0, 0);
    }
  }

  xsq += __shfl_xor(xsq, 16, 64);
  xsq += __shfl_xor(xsq, 32, 64);
  float xnv4[4], art4[4];
  #pragma unroll
  for (int i = 0; i < 4; ++i) {
    float s2 = __shfl(xsq, 4*g + i, 64);
    float xnv = fmaxf(sqrtf(s2), 1e-15f);
    float aa = fminf(xnv, 1.f - 1e-7f);
    xnv4[i] = xnv;
    art4[i] = 0.5f * (log1pf(aa) - log1pf(-aa));
  }

  float bl[8];
  #pragma unroll
  for (int s = 0; s < 8; ++s) bl[s] = bvec[16*(8*w+s) + l15];
  float m2p[4] = {0.f,0.f,0.f,0.f}, mbp[4] = {0.f,0.f,0.f,0.f}, b2p = 0.f;
  #pragma unroll
  for (int s = 0; s < 8; ++s) {
    b2p += bl[s]*bl[s];
    #pragma unroll
    for (int i = 0; i < 4; ++i) {
      m2p[i] = fmaf(acc[s][i], acc[s][i], m2p[i]);
      mbp[i] = fmaf(acc[s][i], bl[s], mbp[i]);
    }
  }
  #pragma unroll
  for (int off = 1; off <= 8; off <<= 1) {
    b2p += __shfl_xor(b2p, off, 64);
    #pragma unroll
    for (int i = 0; i < 4; ++i) {
      m2p[i] += __shfl_xor(m2p[i], off, 64);
      mbp[i] += __shfl_xor(mbp[i], off, 64);
    }
  }
  if (l == 0) smb2[w] = b2p;
  if (l15 == 0) {
    #pragma unroll
    for (int i = 0; i < 4; ++i) { smM[w][g][i] = m2p[i]; smB[w][g][i] = mbp[i]; }
  }
  __syncthreads();
  float b2 = smb2[0] + smb2[1] + smb2[2] + smb2[3];
  #pragma unroll
  for (int i = 0; i < 4; ++i) {
    float m2 = smM[0][g][i]+smM[1][g][i]+smM[2][g][i]+smM[3][g][i];
    float mb = smB[0][g][i]+smB[1][g][i]+smB[2][g][i]+smB[3][g][i];
    float xn = xnv4[i], art = art4[i];
    float mn = fmaxf(sqrtf(m2), 1e-15f);
    float t = tanhf(mn / xn * art);
    float alpha, rn;
    if (m2 > 0.f) { alpha = t / mn; rn = t; } else { alpha = 0.f; rn = 0.f; }
    if (rn > MAXN) { alpha *= MAXN / rn; rn = MAXN; }
    float x2r = rn * rn;
    float xy = alpha * mb;
    float A  = 1.f + 2.f*xy + b2;
    float Bc = 1.f - x2r;
    float den = fmaxf(1.f + 2.f*xy + x2r*b2, 1e-15f);
    float n2v = (A*A*x2r + 2.f*A*Bc*xy + Bc*Bc*b2) / (den*den);
    float nn = fmaxf(sqrtf(n2v), 1e-15f);
    float sc = (nn > MAXN) ? (MAXN / nn) : 1.f;
    float G = sc * A * alpha / den;
    float Hc = sc * Bc / den;
    int grow = R*16 + 4*g + i;
    #pragma unroll
    for (int s = 0; s < 8; ++s)
      outF[(size_t)grow*E_ + 16*(8*w+s) + l15] = G*acc[s][i] + Hc*bl[s];
  }
}

// ---- Attention (r12-proven): 32KB LDS, single-buffer K, V dbuf, rcp-factored.
__global__ __launch_bounds__(256, 4) void attn_kernel(
    const unsigned short* __restrict__ Qhi, const unsigned short* __restrict__ Khi,
    const unsigned short* __restrict__ Vhi,
    const float* __restrict__ qn_arr, const float* __restrict__ kn_arr,
    float* __restrict__ Out) {
  __shared__ __align__(16) unsigned short Kf[4096];
  __shared__ __align__(16) unsigned short Vf[2][4096];
  __shared__ __align__(16) unsigned short Pf[4][1024];

  int tid = threadIdx.x;
  int w = tid >> 6, l = tid & 63;
  int l15 = l & 15, g = l >> 4;

  int bid = blockIdx.x;                 // XCD swizzle: xcd owns bh 4*xcd..4*xcd+3
  int xcd = bid & 7, idx = bid >> 3;
  int bh = xcd * 4 + (idx >> 5);
  int qblk = idx & 31;
  int b = bh >> 3, h = bh & 7;
  int qb = qblk * 64;

  const unsigned short* qbase = Qhi + ((size_t)(bh*32 + qblk))*4096;
  short8 qhi[2];
  #pragma unroll
  for (int dt = 0; dt < 2; ++dt)
    qhi[dt] = *(const short8*)(qbase + (size_t)((dt*4 + w)*64 + l)*8);
  float qnv[4], qd[4], rq[4];
  #pragma unroll
  for (int i = 0; i < 4; ++i) {
    qnv[i] = qn_arr[(size_t)bh*S_ + qb + 16*w + 4*g + i];
    qd[i] = 1.f - qnv[i];
    rq[i] = __builtin_amdgcn_rcpf(qd[i]);
  }

  f32x4 Oacc[4];
  #pragma unroll
  for (int dn = 0; dn < 4; ++dn) Oacc[dn] = (f32x4){0.f,0.f,0.f,0.f};
  float lp[4] = {0.f,0.f,0.f,0.f};

  const unsigned short* Kbh = Khi + ((size_t)bh*32)*4096;
  const unsigned short* Vbh = Vhi + ((size_t)bh*32)*4096;
  const float* knp = kn_arr + (size_t)bh*S_;

  #pragma unroll
  for (int r = 0; r < 2; ++r) {
    gload_lds16(Kbh + r*2048 + w*512 + l*8, &Kf[r*2048 + w*512]);
    gload_lds16(Vbh + r*2048 + w*512 + l*8, &Vf[0][r*2048 + w*512]);
  }
  asm volatile("s_waitcnt vmcnt(0)" ::: "memory");
  __syncthreads();

  #pragma unroll 1
  for (int tile = 0; tile < 32; ++tile) {
    int cur = tile & 1;
    int kb = tile * 64;
    float knc[4];
    #pragma unroll
    for (int n = 0; n < 4; ++n) knc[n] = knp[kb + 16*n + l15];
    #pragma unroll
    for (int n = 0; n < 4; ++n) {
      f32x4 Cn = (f32x4){0.f,0.f,0.f,0.f};
      #pragma unroll
      for (int dt = 0; dt < 2; ++dt) {
        short8 kfr = *(const short8*)&Kf[((dt*4 + n)*64 + l)*8];
        Cn = __builtin_amdgcn_mfma_f32_16x16x32_bf16(qhi[dt], kfr, Cn, 0, 0, 0);
      }
      float kd = 1.f - knc[n];
      float rkn = __builtin_amdgcn_rcpf(kd);
      int cbase = (n >> 1)*64 + 16*((2*n + (l15 >> 3)) & 3) + 4*g;
      int csb = cbase ^ ((cbase >> 3) & 7);
      int j7 = l15 & 7;
      #pragma unroll
      for (int i = 0; i < 4; ++i) {
        float num = fmaf(-qnv[i], knc[n], Cn[i]);
        float d2 = fmaxf(num * (rq[i]*rkn), 5e-6f);
        float sq = d2 * __builtin_amdgcn_rsqf(d2);
        float p = __builtin_amdgcn_exp2f(-0.25503386f * sq);
        unsigned u = __float_as_uint(p);
        lp[i] += __uint_as_float(u & 0xffff0000u);
        Pf[w][((csb ^ i) << 3) + j7] = (unsigned short)(u >> 16);
      }
    }
    __builtin_amdgcn_s_barrier();
    if (tile < 31) {
      const unsigned short* kp = Kbh + ((size_t)(tile+1))*4096;
      const unsigned short* vp = Vbh + ((size_t)(tile+1))*4096;
      #pragma unroll
      for (int r = 0; r < 2; ++r)
        gload_lds16(kp + r*2048 + w*512 + l*8, &Kf[r*2048 + w*512]);
      #pragma unroll
      for (int r = 0; r < 2; ++r)
        gload_lds16(vp + r*2048 + w*512 + l*8, &Vf[cur^1][r*2048 + w*512]);
    }
    __builtin_amdgcn_sched_barrier(0);
    short8 pa0, pa1;
    { int c = l;       int cs = c ^ ((c >> 3) & 7); pa0 = *(const short8*)&Pf[w][cs*8]; }
    { int c = 64 + l;  int cs = c ^ ((c >> 3) & 7); pa1 = *(const short8*)&Pf[w][cs*8]; }
    #pragma unroll
    for (int dn = 0; dn < 4; ++dn) {
      short8 v0 = *(const short8*)&Vf[cur][((0*4 + dn)*64 + l)*8];
      short8 v1 = *(const short8*)&Vf[cur][((1*4 + dn)*64 + l)*8];
      f32x4 o = Oacc[dn];
      o = __builtin_amdgcn_mfma_f32_16x16x32_bf16(pa0, v0, o, 0, 0, 0);
      o = __builtin_amdgcn_mfma_f32_16x16x32_bf16(pa1, v1, o, 0, 0, 0);
      Oacc[dn] = o;
    }
    asm volatile("s_waitcnt vmcnt(2)" ::: "memory");
    __builtin_amdgcn_s_barrier();
  }

  #pragma unroll
  for (int i = 0; i < 4; ++i) {
    lp[i] += __shfl_xor(lp[i], 1, 64);
    lp[i] += __shfl_xor(lp[i], 2, 64);
    lp[i] += __shfl_xor(lp[i], 4, 64);
    lp[i] += __shfl_xor(lp[i], 8, 64);
    lp[i] = 1.f / lp[i];
  }
  #pragma unroll
  for (int i = 0; i < 4; ++i) {
    size_t orow = (size_t)(b*S_ + qb + 16*w + 4*g + i)*E_ + h*Dh_;
    #pragma unroll
    for (int dn = 0; dn < 4; ++dn)
      Out[orow + 16*dn + l15] = Oacc[dn][i] * lp[i];
  }
}

extern "C" void kernel_launch(void* const* d_in, const int* in_sizes, int n_in,
                              void* d_out, int out_size, void* d_ws, size_t ws_size,
                              hipStream_t stream) {
  const float* x  = (const float*)d_in[0];
  const float* Wq = (const float*)d_in[1];
  const float* bq = (const float*)d_in[2];
  const float* Wk = (const float*)d_in[3];
  const float* bk = (const float*)d_in[4];
  const float* Wv = (const float*)d_in[5];
  const float* bv = (const float*)d_in[6];
  const float* Wo = (const float*)d_in[7];
  const float* bo = (const float*)d_in[8];
  float* out = (float*)d_out;

  char* p = (char*)d_ws;
  unsigned short* Wp  = (unsigned short*)p; p += (size_t)2  << 20;  // 2 MB (hi only)
  unsigned short* Qhi = (unsigned short*)p; p += (size_t)8  << 20;
  unsigned short* Khi = (unsigned short*)p; p += (size_t)8  << 20;
  unsigned short* Vhi = (unsigned short*)p; p += (size_t)8  << 20;
  float* ao   = (float*)p; p += (size_t)16 << 20;                   // attn out fp32
  float* qn   = (float*)p; p += (size_t)B_*H_*S_ * 4;
  float* kn   = (float*)p; p += (size_t)B_*H_*S_ * 4;
  // total ~= 42.5 MB

  pack_w_kernel<<<dim3(32, 4), dim3(256), 0, stream>>>(Wq, Wk, Wv, Wo, Wp);
  qkv_linear<<<dim3(BS_/16, 3), dim3(256), 0, stream>>>(x, Wp, bq, bk, bv, Qhi, Khi, Vhi, qn, kn);
  attn_kernel<<<dim3(1024), dim3(256), 0, stream>>>(Qhi, Khi, Vhi, qn, kn, ao);
  o_linear<<<dim3(BS_/16), dim3(256), 0, stream>>>(ao, Wp + 3*262144, bo, out);
}